// Round 2
// baseline (1343.702 us; speedup 1.0000x reference)
//
#include <hip/hip_runtime.h>
#include <stdint.h>

// VisionBlock: LN1 -> QKV GEMM -> RoPE -> windowed attn (W=64) -> proj+res -> LN2 -> GELU MLP + res
// bf16 MFMA 16x16x32, fp32 accumulate.
// GEMM v3 (m201-style 8-phase): 256x256 tile, BK=64, 512 threads = 8 waves (2M x 4N),
// per-wave 128x64 out (acc[8][4]). LDS = 2 K-tile buffers x 64 KB = 128 KB.
// 4 phases per K-tile: {ds_read frags; stage 1 half-tile (2 gload_lds/thread);
// counted vmcnt(4) at phases 1,3; s_barrier; lgkmcnt(0); setprio+16 MFMA; s_barrier}.
// vmcnt never drains to 0 in steady state. XOR bank swizzle, XCD-grouped m-strip-major tiles.
// N padded to 256 multiples via zero-filled weight buffers + col<Nout store guards.

#define SEQ   16384
#define HID   1152
#define NH    16
#define HDIM  72
#define INTER 4304
#define INTERP 4352
#define QKVN  3456

using bf16x8 = __attribute__((ext_vector_type(8))) __bf16;
using f32x4  = __attribute__((ext_vector_type(4))) float;

__device__ __forceinline__ float bf2f(uint16_t u){ return __uint_as_float(((uint32_t)u)<<16); }
__device__ __forceinline__ uint16_t f2bf(float f){
  uint32_t u = __float_as_uint(f);
  u += 0x7fffu + ((u>>16)&1u);
  return (uint16_t)(u>>16);
}
__device__ __forceinline__ float gelu_tanh(float x){
  float t = tanhf(0.7978845608028654f*(x + 0.044715f*x*x*x));
  return 0.5f*x*(1.0f + t);
}
__device__ __forceinline__ void async_load16(const void* g, void* l){
  __builtin_amdgcn_global_load_lds((__attribute__((address_space(1))) void*)(void*)g,
                                   (__attribute__((address_space(3))) void*)l, 16, 0, 0);
}

// ---------------- transpose + cast fp32[R][C] -> bf16[Cp][Rp], zero-padded ----------------
__global__ void transpose_cast(const float* __restrict__ src, uint16_t* __restrict__ dst,
                               int R, int C, int Rp)
{
  __shared__ float tile[32][33];
  const int tx = threadIdx.x & 31, ty = threadIdx.x >> 5;
  const int c = blockIdx.x*32 + tx;
  #pragma unroll
  for (int s = 0; s < 4; ++s){
    const int r = blockIdx.y*32 + ty + s*8;
    tile[ty + s*8][tx] = (r < R && c < C) ? src[(size_t)r*C + c] : 0.0f;
  }
  __syncthreads();
  #pragma unroll
  for (int s = 0; s < 4; ++s){
    const int oc = blockIdx.x*32 + ty + s*8;     // output row  (N dim)
    const int orr = blockIdx.y*32 + tx;          // output col  (K dim)
    dst[(size_t)oc*Rp + orr] = f2bf(tile[tx][ty + s*8]);
  }
}

// ---------------- LayerNorm: fp32 in -> bf16 out, one wave per row ----------------
__global__ void ln_kernel(const float* __restrict__ x, const float* __restrict__ w,
                          const float* __restrict__ b, uint16_t* __restrict__ out)
{
  const int wid = threadIdx.x >> 6, lane = threadIdx.x & 63;
  const int row = blockIdx.x*4 + wid;
  const float* xr = x + (size_t)row*HID;
  float v[18];
  float s = 0.f;
  #pragma unroll
  for (int t = 0; t < 18; ++t){ v[t] = xr[lane + t*64]; s += v[t]; }
  #pragma unroll
  for (int m = 32; m; m >>= 1) s += __shfl_xor(s, m, 64);
  const float mean = s * (1.0f/HID);
  float q = 0.f;
  #pragma unroll
  for (int t = 0; t < 18; ++t){ float d = v[t]-mean; q += d*d; }
  #pragma unroll
  for (int m = 32; m; m >>= 1) q += __shfl_xor(q, m, 64);
  const float rstd = rsqrtf(q*(1.0f/HID) + 1e-6f);
  uint16_t* orow = out + (size_t)row*HID;
  #pragma unroll
  for (int t = 0; t < 18; ++t){
    const int j = lane + t*64;
    orow[j] = f2bf((v[t]-mean)*rstd*w[j] + b[j]);
  }
}

// ---------------- RoPE in-place on bf16 qkv [SEQ][3456] (q,k only) ----------------
__global__ void rope_kernel(uint16_t* __restrict__ qkv, const float* __restrict__ cosb,
                            const float* __restrict__ sinb)
{
  const int idx = blockIdx.x*256 + threadIdx.x;      // SEQ*NH*36 threads exactly
  const int s  = idx / (NH*36);
  const int r1 = idx - s*(NH*36);
  const int h  = r1 / 36;
  const int d  = r1 - h*36;
  const float c  = cosb[s*HDIM + d];
  const float sn = sinb[s*HDIM + d];
  const size_t b = (size_t)s*QKVN + h*HDIM + d;
  float q1 = bf2f(qkv[b]), q2 = bf2f(qkv[b+36]);
  qkv[b]    = f2bf(q1*c - q2*sn);
  qkv[b+36] = f2bf(q2*c + q1*sn);
  float k1 = bf2f(qkv[b+HID]), k2 = bf2f(qkv[b+HID+36]);
  qkv[b+HID]    = f2bf(k1*c - k2*sn);
  qkv[b+HID+36] = f2bf(k2*c + k1*sn);
}

// ---------------- windowed attention: one block per (window, head) ----------------
__global__ __launch_bounds__(256,2) void attn_kernel(const uint16_t* __restrict__ qkv,
                                                     uint16_t* __restrict__ outb)
{
  __shared__ float Q[64*76];
  __shared__ float K[64*76];
  __shared__ float V[64*76];
  __shared__ float P[64*68];
  const int tid = threadIdx.x;
  const int win = blockIdx.x >> 4, h = blockIdx.x & 15;
  const size_t base = (size_t)win*64*QKVN + h*HDIM;
  {
    const int r = tid >> 2, q4 = tid & 3;
    const size_t rb = base + (size_t)r*QKVN;
    #pragma unroll
    for (int p0 = 0; p0 < 9; ++p0){
      const int p = q4*9 + p0;
      const uint32_t uq = *(const uint32_t*)(qkv + rb + 2*p);
      const uint32_t uk = *(const uint32_t*)(qkv + rb + HID + 2*p);
      const uint32_t uv = *(const uint32_t*)(qkv + rb + 2*HID + 2*p);
      Q[r*76+2*p] = bf2f((uint16_t)uq); Q[r*76+2*p+1] = bf2f((uint16_t)(uq>>16));
      K[r*76+2*p] = bf2f((uint16_t)uk); K[r*76+2*p+1] = bf2f((uint16_t)(uk>>16));
      V[r*76+2*p] = bf2f((uint16_t)uv); V[r*76+2*p+1] = bf2f((uint16_t)(uv>>16));
    }
  }
  __syncthreads();
  const int rg = tid >> 4, cg = tid & 15;
  const int r0 = rg*4, c0 = cg*4;
  float sc[4][4] = {};
  #pragma unroll 3
  for (int kk = 0; kk < 18; ++kk){
    float4 qv[4], kv[4];
    #pragma unroll
    for (int i = 0; i < 4; ++i) qv[i] = *(const float4*)&Q[(r0+i)*76 + kk*4];
    #pragma unroll
    for (int j = 0; j < 4; ++j) kv[j] = *(const float4*)&K[(c0+j)*76 + kk*4];
    #pragma unroll
    for (int i = 0; i < 4; ++i)
      #pragma unroll
      for (int j = 0; j < 4; ++j)
        sc[i][j] += qv[i].x*kv[j].x + qv[i].y*kv[j].y + qv[i].z*kv[j].z + qv[i].w*kv[j].w;
  }
  const float scale = 0.11785113019775793f;   // 72^-0.5
  #pragma unroll
  for (int i = 0; i < 4; ++i){
    float a0 = sc[i][0]*scale, a1 = sc[i][1]*scale, a2 = sc[i][2]*scale, a3 = sc[i][3]*scale;
    float m = fmaxf(fmaxf(a0,a1), fmaxf(a2,a3));
    m = fmaxf(m, __shfl_xor(m, 1, 16));
    m = fmaxf(m, __shfl_xor(m, 2, 16));
    m = fmaxf(m, __shfl_xor(m, 4, 16));
    m = fmaxf(m, __shfl_xor(m, 8, 16));
    float e0 = __expf(a0-m), e1 = __expf(a1-m), e2 = __expf(a2-m), e3 = __expf(a3-m);
    float sm = e0+e1+e2+e3;
    sm += __shfl_xor(sm, 1, 16);
    sm += __shfl_xor(sm, 2, 16);
    sm += __shfl_xor(sm, 4, 16);
    sm += __shfl_xor(sm, 8, 16);
    const float inv = 1.0f/sm;
    *(float4*)&P[(r0+i)*68 + c0] = make_float4(e0*inv, e1*inv, e2*inv, e3*inv);
  }
  __syncthreads();
  for (int d4 = cg; d4 < 18; d4 += 16){
    float4 o[4] = {};
    #pragma unroll 4
    for (int k4 = 0; k4 < 16; ++k4){
      float4 pr[4];
      #pragma unroll
      for (int i = 0; i < 4; ++i) pr[i] = *(const float4*)&P[(r0+i)*68 + k4*4];
      const float4 v0 = *(const float4*)&V[(k4*4+0)*76 + d4*4];
      const float4 v1 = *(const float4*)&V[(k4*4+1)*76 + d4*4];
      const float4 v2 = *(const float4*)&V[(k4*4+2)*76 + d4*4];
      const float4 v3 = *(const float4*)&V[(k4*4+3)*76 + d4*4];
      #pragma unroll
      for (int i = 0; i < 4; ++i){
        o[i].x += pr[i].x*v0.x + pr[i].y*v1.x + pr[i].z*v2.x + pr[i].w*v3.x;
        o[i].y += pr[i].x*v0.y + pr[i].y*v1.y + pr[i].z*v2.y + pr[i].w*v3.y;
        o[i].z += pr[i].x*v0.z + pr[i].y*v1.z + pr[i].z*v2.z + pr[i].w*v3.z;
        o[i].w += pr[i].x*v0.w + pr[i].y*v1.w + pr[i].z*v2.w + pr[i].w*v3.w;
      }
    }
    #pragma unroll
    for (int i = 0; i < 4; ++i){
      const int token = win*64 + r0 + i;
      const size_t ob = (size_t)token*HID + h*HDIM + d4*4;
      outb[ob+0] = f2bf(o[i].x); outb[ob+1] = f2bf(o[i].y);
      outb[ob+2] = f2bf(o[i].z); outb[ob+3] = f2bf(o[i].w);
    }
  }
}

// ---------------- bf16 GEMM v3: C[M][N] = A[M][K] @ Bt[N][K]^T ----------------
// 256x256 tile, BK=64. LDS per K-tile buffer: A 32 chunks + B 32 chunks of
// (16 rows x 32 k-cols) bf16, 1 KB each; physical 8-elem slot k holds logical
// chunk k ^ ((row>>1)&3) (conflict-free ds_read_b128, verified 0 conflicts).
// Wave wid stages A/B row-chunks {wid*2, wid*2+1}; per half-tile (one h of A or B)
// each thread issues 2 global_load_lds. 4 phases per K-tile (mh,h):
//   p0(m0,k0): read 4A+4B frags | stage A-k0(t+1) | barrier | lgkm0 | 16 MFMA | barrier
//   p1(m1,k0): read 4A (B reuse) | stage B-k0(t+1) | vmcnt(4) | barrier | ... MFMA | barrier
//   p2(m0,k1): read 4A+4B | stage A-k1(t+1) | barrier | ... | barrier
//   p3(m1,k1): read 4A | stage B-k1(t+1) | vmcnt(4) | barrier | ... | barrier
// vmcnt(4) = leave newest 2 half-tiles (4 loads/thread) in flight; validates the
// halves needed 1 phase later. Buffer reuse is fenced by each phase's lgkm0+barrier.
// EPI: 0 = bf16(bias), 1 = bf16(gelu(bias)), 2 = f32(bias + residual)
template<int EPI>
__global__ __launch_bounds__(512,2) void gemm_bt(
    const uint16_t* __restrict__ A, const uint16_t* __restrict__ Bt,
    const float* __restrict__ bias, int Nb,
    const float* res, void* outp, int N, int Nout, int K, int NB)
{
  __shared__ uint16_t sM[2*32768];   // 2 buffers x (A 16K + B 16K elems) = 128 KB
  const int tid = threadIdx.x, wid = tid >> 6, lane = tid & 63;
  // XCD-grouped tile id (grid multiple of 8; m-strip-major within an XCD's run)
  const int per  = gridDim.x >> 3;
  const int tile = (blockIdx.x & 7)*per + (blockIdx.x >> 3);
  const int mb   = tile / NB;
  const int mBase = mb*256, nBase = (tile - mb*NB)*256;
  const int wm = wid >> 2, wn = wid & 3;
  // staging lane mapping (lane -> row sr, physical slot sk; fetch logical chunk gk)
  const int sr = lane >> 2, sk = lane & 3, gk = sk ^ ((sr >> 1) & 3);
  // fragment read mapping (row rr, logical k-quad rq at physical slot rp)
  const int rr = lane & 15, rq = lane >> 4, rp = rq ^ ((rr >> 1) & 3);

  // global srcs for this thread's staged chunks (row-chunks wid*2, wid*2+1)
  const uint16_t* pA0 = A  + (size_t)(mBase + (wid*2+0)*16 + sr)*K + gk*8;
  const uint16_t* pA1 = A  + (size_t)(mBase + (wid*2+1)*16 + sr)*K + gk*8;
  const uint16_t* pB0 = Bt + (size_t)(nBase + (wid*2+0)*16 + sr)*K + gk*8;
  const uint16_t* pB1 = Bt + (size_t)(nBase + (wid*2+1)*16 + sr)*K + gk*8;
  const int c0 = (wid*2+0)*2, c1 = (wid*2+1)*2;   // chunk slots (x2 for h)

  auto stageA = [&](int b, int h, int koff){
    uint16_t* sl = &sM[b*32768];
    async_load16(pA0 + koff + h*32, &sl[(c0+h)*512]);
    async_load16(pA1 + koff + h*32, &sl[(c1+h)*512]);
  };
  auto stageB = [&](int b, int h, int koff){
    uint16_t* sl = &sM[b*32768 + 16384];
    async_load16(pB0 + koff + h*32, &sl[(c0+h)*512]);
    async_load16(pB1 + koff + h*32, &sl[(c1+h)*512]);
  };

  const int NT = K >> 6;
  f32x4 acc[8][4] = {};

  // prologue: stage K-tile 0 (4 half-tiles, 8 loads/thread); validate k0 halves
  stageA(0,0,0); stageB(0,0,0); stageA(0,1,0); stageB(0,1,0);
  asm volatile("s_waitcnt vmcnt(4)" ::: "memory");
  __builtin_amdgcn_s_barrier();

  int k0 = 64;
  const int aB = wm*8;
  for (int t = 0; t < NT; ++t){
    const uint16_t* sl = &sM[(t&1)*32768];
    const int nb2 = (t&1)^1;
    const bool pf = (t+1 < NT);
    bf16x8 af[4], bfr[4];
    // ---------- phase 0: mh=0, h=0 ----------
    #pragma unroll
    for (int i=0;i<4;++i) af[i]  = *(const bf16x8*)&sl[((aB+i)*2+0)*512 + rr*32 + rp*8];
    #pragma unroll
    for (int j=0;j<4;++j) bfr[j] = *(const bf16x8*)&sl[16384 + ((wn*4+j)*2+0)*512 + rr*32 + rp*8];
    if (pf) stageA(nb2, 0, k0);
    __builtin_amdgcn_s_barrier();
    asm volatile("s_waitcnt lgkmcnt(0)" ::: "memory");
    __builtin_amdgcn_s_setprio(1);
    #pragma unroll
    for (int i=0;i<4;++i)
      #pragma unroll
      for (int j=0;j<4;++j)
        acc[i][j] = __builtin_amdgcn_mfma_f32_16x16x32_bf16(af[i], bfr[j], acc[i][j], 0, 0, 0);
    __builtin_amdgcn_s_setprio(0);
    __builtin_amdgcn_s_barrier();
    // ---------- phase 1: mh=1, h=0 (B frags reused) ----------
    #pragma unroll
    for (int i=0;i<4;++i) af[i]  = *(const bf16x8*)&sl[((aB+4+i)*2+0)*512 + rr*32 + rp*8];
    if (pf){ stageB(nb2, 0, k0);
             asm volatile("s_waitcnt vmcnt(4)" ::: "memory"); }   // k1(t) landed
    else   { asm volatile("s_waitcnt vmcnt(0)" ::: "memory"); }
    __builtin_amdgcn_s_barrier();
    asm volatile("s_waitcnt lgkmcnt(0)" ::: "memory");
    __builtin_amdgcn_s_setprio(1);
    #pragma unroll
    for (int i=0;i<4;++i)
      #pragma unroll
      for (int j=0;j<4;++j)
        acc[4+i][j] = __builtin_amdgcn_mfma_f32_16x16x32_bf16(af[i], bfr[j], acc[4+i][j], 0, 0, 0);
    __builtin_amdgcn_s_setprio(0);
    __builtin_amdgcn_s_barrier();
    // ---------- phase 2: mh=0, h=1 ----------
    #pragma unroll
    for (int i=0;i<4;++i) af[i]  = *(const bf16x8*)&sl[((aB+i)*2+1)*512 + rr*32 + rp*8];
    #pragma unroll
    for (int j=0;j<4;++j) bfr[j] = *(const bf16x8*)&sl[16384 + ((wn*4+j)*2+1)*512 + rr*32 + rp*8];
    if (pf) stageA(nb2, 1, k0);
    __builtin_amdgcn_s_barrier();
    asm volatile("s_waitcnt lgkmcnt(0)" ::: "memory");
    __builtin_amdgcn_s_setprio(1);
    #pragma unroll
    for (int i=0;i<4;++i)
      #pragma unroll
      for (int j=0;j<4;++j)
        acc[i][j] = __builtin_amdgcn_mfma_f32_16x16x32_bf16(af[i], bfr[j], acc[i][j], 0, 0, 0);
    __builtin_amdgcn_s_setprio(0);
    __builtin_amdgcn_s_barrier();
    // ---------- phase 3: mh=1, h=1 (B frags reused) ----------
    #pragma unroll
    for (int i=0;i<4;++i) af[i]  = *(const bf16x8*)&sl[((aB+4+i)*2+1)*512 + rr*32 + rp*8];
    if (pf){ stageB(nb2, 1, k0);
             asm volatile("s_waitcnt vmcnt(4)" ::: "memory"); }   // k0(t+1) landed
    __builtin_amdgcn_s_barrier();
    asm volatile("s_waitcnt lgkmcnt(0)" ::: "memory");
    __builtin_amdgcn_s_setprio(1);
    #pragma unroll
    for (int i=0;i<4;++i)
      #pragma unroll
      for (int j=0;j<4;++j)
        acc[4+i][j] = __builtin_amdgcn_mfma_f32_16x16x32_bf16(af[i], bfr[j], acc[4+i][j], 0, 0, 0);
    __builtin_amdgcn_s_setprio(0);
    __builtin_amdgcn_s_barrier();
    k0 += 64;
  }

  const int rqd = (lane>>4)*4, cl = lane & 15;
  #pragma unroll
  for (int i8 = 0; i8 < 8; ++i8){
    #pragma unroll
    for (int j = 0; j < 4; ++j){
      const int col = nBase + wn*64 + j*16 + cl;
      if (col < Nout){
        const float bv = (col < Nb) ? bias[col] : 0.0f;
        #pragma unroll
        for (int r = 0; r < 4; ++r){
          const int row = mBase + wm*128 + i8*16 + rqd + r;
          const float v = acc[i8][j][r] + bv;
          const size_t o = (size_t)row*N + col;
          if (EPI == 0)      ((uint16_t*)outp)[o] = f2bf(v);
          else if (EPI == 1) ((uint16_t*)outp)[o] = f2bf(gelu_tanh(v));
          else               ((float*)outp)[o] = v + res[o];
        }
      }
    }
  }
}

// ---------------- host launcher ----------------
extern "C" void kernel_launch(void* const* d_in, const int* in_sizes, int n_in,
                              void* d_out, int out_size, void* d_ws, size_t ws_size,
                              hipStream_t stream)
{
  const float* x      = (const float*)d_in[0];
  const float* cosb   = (const float*)d_in[1];
  const float* sinb   = (const float*)d_in[2];
  const float* qkv_w  = (const float*)d_in[4];
  const float* qkv_b  = (const float*)d_in[5];
  const float* proj_w = (const float*)d_in[6];
  const float* proj_b = (const float*)d_in[7];
  const float* ln1_w  = (const float*)d_in[8];
  const float* ln1_b  = (const float*)d_in[9];
  const float* ln2_w  = (const float*)d_in[10];
  const float* ln2_b  = (const float*)d_in[11];
  const float* fc1_w  = (const float*)d_in[12];
  const float* fc1_b  = (const float*)d_in[13];
  const float* fc2_w  = (const float*)d_in[14];
  const float* fc2_b  = (const float*)d_in[15];

  char* ws = (char*)d_ws;
  uint16_t* Wqkv  = (uint16_t*)(ws + 0);          // [3584][1152] bf16 (3456 padded)
  uint16_t* Wproj = (uint16_t*)(ws + 8257536);    // [1280][1152] bf16 (1152 padded)
  uint16_t* Wfc1  = (uint16_t*)(ws + 11206656);   // [4352][1152] bf16 (4304 padded)
  uint16_t* Wfc2  = (uint16_t*)(ws + 21233664);   // [1280][4352] bf16 (1152 padded)
  uint16_t* Hbuf  = (uint16_t*)(ws + 32374784);   // [16384][1152] bf16 (LN out / attn out)
  uint16_t* QKV   = (uint16_t*)(ws + 70123520);   // [16384][3456] bf16
  uint16_t* MB    = QKV;                          // [16384][4352] bf16 overlays QKV
  float* X1 = (float*)d_out;                      // fp32 [16384][1152], residual stream

  // weight transpose+cast (Bt layout [Npad][K], zero-padded rows and cols)
  transpose_cast<<<dim3(112,36), 256, 0, stream>>>(qkv_w, Wqkv, 1152, 3456, 1152);
  transpose_cast<<<dim3(40,36),  256, 0, stream>>>(proj_w, Wproj, 1152, 1152, 1152);
  transpose_cast<<<dim3(136,36), 256, 0, stream>>>(fc1_w, Wfc1, 1152, 4304, 1152);
  transpose_cast<<<dim3(40,136), 256, 0, stream>>>(fc2_w, Wfc2, 4304, 1152, 4352);

  // LN1 -> Hbuf (bf16)
  ln_kernel<<<4096, 256, 0, stream>>>(x, ln1_w, ln1_b, Hbuf);
  // QKV = Hbuf @ Wqkv^T + b -> bf16   (64 m x 14 n tiles, Nout=3456)
  gemm_bt<0><<<64*14, 512, 0, stream>>>(Hbuf, Wqkv, qkv_b, QKVN, nullptr, QKV, QKVN, QKVN, HID, 14);
  // RoPE in place on q,k
  rope_kernel<<<36864, 256, 0, stream>>>(QKV, cosb, sinb);
  // windowed attention -> Hbuf (bf16)
  attn_kernel<<<4096, 256, 0, stream>>>(QKV, Hbuf);
  // X1 = x + Hbuf @ Wproj^T + b  (fp32, into d_out)   (64 x 5, Nout=1152)
  gemm_bt<2><<<64*5, 512, 0, stream>>>(Hbuf, Wproj, proj_b, HID, x, X1, HID, HID, HID, 5);
  // LN2 -> Hbuf (bf16)
  ln_kernel<<<4096, 256, 0, stream>>>(X1, ln2_w, ln2_b, Hbuf);
  // MB = gelu(Hbuf @ Wfc1^T + b)  (bf16, write padded N=4352 so fc2 K-pad is zero)
  gemm_bt<1><<<64*17, 512, 0, stream>>>(Hbuf, Wfc1, fc1_b, INTER, nullptr, MB, INTERP, INTERP, HID, 17);
  // out = X1 + MB @ Wfc2^T + b   (fp32, in-place on d_out)   (64 x 5, Nout=1152)
  gemm_bt<2><<<64*5, 512, 0, stream>>>(MB, Wfc2, fc2_b, HID, X1, X1, HID, HID, INTERP, 5);
}

// Round 3
// 1160.024 us; speedup vs baseline: 1.1583x; 1.1583x over previous
//
#include <hip/hip_runtime.h>
#include <stdint.h>

// VisionBlock: LN1 -> QKV GEMM -> [RoPE fused into attn] -> windowed attn (W=64) -> proj+res -> LN2 -> GELU MLP + res
// bf16 MFMA 16x16x32, fp32 accumulate. 128x128 tile, BK=64, global_load_lds width=16,
// XOR bank-conflict swizzle, XCD-grouped tile assignment, 3 blocks/CU (proven 582 TF core).
// v3 changes: rope_kernel deleted (RoPE applied during attn LDS staging, using cos[d]==cos[d+36]);
// GELU via sigmoid/exp2 (no tanhf); LN vectorized float2.

#define SEQ   16384
#define HID   1152
#define NH    16
#define HDIM  72
#define INTER 4304
#define INTERP 4352
#define QKVN  3456

using bf16x8 = __attribute__((ext_vector_type(8))) __bf16;
using f32x4  = __attribute__((ext_vector_type(4))) float;

__device__ __forceinline__ float bf2f(uint16_t u){ return __uint_as_float(((uint32_t)u)<<16); }
__device__ __forceinline__ uint16_t f2bf(float f){
  uint32_t u = __float_as_uint(f);
  u += 0x7fffu + ((u>>16)&1u);
  return (uint16_t)(u>>16);
}
// 0.5x(1+tanh(0.79788456(x+0.044715x^3))) == x*sigmoid(1.59576912(x+0.044715x^3))
// sigmoid(z) = 1/(1+exp2(-z*log2e)); 1.5957691216*1.4426950409 = 2.3022085
__device__ __forceinline__ float gelu_fast(float x){
  const float z = 2.3022085f * x * (1.0f + 0.044715f*x*x);
  return x / (1.0f + exp2f(-z));
}
__device__ __forceinline__ void async_load16(const void* g, void* l){
  __builtin_amdgcn_global_load_lds((__attribute__((address_space(1))) void*)(void*)g,
                                   (__attribute__((address_space(3))) void*)l, 16, 0, 0);
}

// ---------------- transpose + cast fp32[R][C] -> bf16[Cp][Rp], zero-padded ----------------
__global__ void transpose_cast(const float* __restrict__ src, uint16_t* __restrict__ dst,
                               int R, int C, int Rp)
{
  __shared__ float tile[32][33];
  const int tx = threadIdx.x & 31, ty = threadIdx.x >> 5;
  const int c = blockIdx.x*32 + tx;
  #pragma unroll
  for (int s = 0; s < 4; ++s){
    const int r = blockIdx.y*32 + ty + s*8;
    tile[ty + s*8][tx] = (r < R && c < C) ? src[(size_t)r*C + c] : 0.0f;
  }
  __syncthreads();
  #pragma unroll
  for (int s = 0; s < 4; ++s){
    const int oc = blockIdx.x*32 + ty + s*8;     // output row  (N dim)
    const int orr = blockIdx.y*32 + tx;          // output col  (K dim)
    dst[(size_t)oc*Rp + orr] = f2bf(tile[tx][ty + s*8]);
  }
}

// ---------------- LayerNorm: fp32 in -> bf16 out, one wave per row (float2 vectorized) ----------------
__global__ void ln_kernel(const float* __restrict__ x, const float* __restrict__ w,
                          const float* __restrict__ b, uint16_t* __restrict__ out)
{
  const int wid = threadIdx.x >> 6, lane = threadIdx.x & 63;
  const int row = blockIdx.x*4 + wid;
  const float2* xr = (const float2*)(x + (size_t)row*HID);
  float2 v[9];
  float s = 0.f;
  #pragma unroll
  for (int t = 0; t < 9; ++t){ v[t] = xr[lane + t*64]; s += v[t].x + v[t].y; }
  #pragma unroll
  for (int m = 32; m; m >>= 1) s += __shfl_xor(s, m, 64);
  const float mean = s * (1.0f/HID);
  float q = 0.f;
  #pragma unroll
  for (int t = 0; t < 9; ++t){
    float dx = v[t].x-mean, dy = v[t].y-mean;
    q += dx*dx + dy*dy;
  }
  #pragma unroll
  for (int m = 32; m; m >>= 1) q += __shfl_xor(q, m, 64);
  const float rstd = rsqrtf(q*(1.0f/HID) + 1e-6f);
  const float2* w2 = (const float2*)w;
  const float2* b2 = (const float2*)b;
  uint32_t* orow = (uint32_t*)(out + (size_t)row*HID);
  #pragma unroll
  for (int t = 0; t < 9; ++t){
    const int j = lane + t*64;
    const float2 wv = w2[j], bv = b2[j];
    const float o0 = (v[t].x-mean)*rstd*wv.x + bv.x;
    const float o1 = (v[t].y-mean)*rstd*wv.y + bv.y;
    orow[j] = (uint32_t)f2bf(o0) | ((uint32_t)f2bf(o1)<<16);
  }
}

// ---------------- windowed attention with fused RoPE: one block per (window, head) ----------------
// RoPE: for d<36, q'[d] = q[d]*cos[d] - q[d+36]*sin[d]; q'[d+36] = q[d+36]*cos[d] + q[d]*sin[d]
// (cos/sin tables satisfy cos[d+36]==cos[d] since emb = concat(ang, ang)). Applied to q,k while
// staging into LDS (f32), so the separate rope pass over 150 MB is eliminated.
__global__ __launch_bounds__(256,2) void attn_kernel(const uint16_t* __restrict__ qkv,
                                                     const float* __restrict__ cosb,
                                                     const float* __restrict__ sinb,
                                                     uint16_t* __restrict__ outb)
{
  __shared__ float Q[64*76];
  __shared__ float K[64*76];
  __shared__ float V[64*76];
  __shared__ float P[64*68];
  const int tid = threadIdx.x;
  const int win = blockIdx.x >> 4, h = blockIdx.x & 15;
  const size_t base = (size_t)win*64*QKVN + h*HDIM;
  {
    const int r = tid >> 2, q4 = tid & 3;
    const size_t rb = base + (size_t)r*QKVN;
    const float* crow = cosb + (size_t)(win*64 + r)*HDIM;
    const float* srow = sinb + (size_t)(win*64 + r)*HDIM;
    // q4 0,1 -> Q pair-halves; q4 2,3 -> K pair-halves (9 uint32 pairs each, d0 = 0..34 even)
    const int isK = q4 >> 1;
    const size_t mb = rb + (size_t)(isK ? HID : 0);
    float* dst = isK ? &K[r*76] : &Q[r*76];
    const int pb = (q4 & 1)*9;
    #pragma unroll
    for (int p0 = 0; p0 < 9; ++p0){
      const int d0 = (pb + p0)*2;
      const uint32_t ulo = *(const uint32_t*)(qkv + mb + d0);
      const uint32_t uhi = *(const uint32_t*)(qkv + mb + d0 + 36);
      const float2 c2 = *(const float2*)(crow + d0);
      const float2 s2 = *(const float2*)(srow + d0);
      const float l0 = bf2f((uint16_t)ulo), l1 = bf2f((uint16_t)(ulo>>16));
      const float h0 = bf2f((uint16_t)uhi), h1 = bf2f((uint16_t)(uhi>>16));
      dst[d0]    = l0*c2.x - h0*s2.x;
      dst[d0+1]  = l1*c2.y - h1*s2.y;
      dst[d0+36] = h0*c2.x + l0*s2.x;
      dst[d0+37] = h1*c2.y + l1*s2.y;
    }
    // V: no rope; all four q4 lanes cover 36 uint32 per row
    #pragma unroll
    for (int p0 = 0; p0 < 9; ++p0){
      const int p = q4*9 + p0;
      const uint32_t uv = *(const uint32_t*)(qkv + rb + 2*HID + 2*p);
      V[r*76+2*p] = bf2f((uint16_t)uv); V[r*76+2*p+1] = bf2f((uint16_t)(uv>>16));
    }
  }
  __syncthreads();
  const int rg = tid >> 4, cg = tid & 15;
  const int r0 = rg*4, c0 = cg*4;
  float sc[4][4] = {};
  #pragma unroll 3
  for (int kk = 0; kk < 18; ++kk){
    float4 qv[4], kv[4];
    #pragma unroll
    for (int i = 0; i < 4; ++i) qv[i] = *(const float4*)&Q[(r0+i)*76 + kk*4];
    #pragma unroll
    for (int j = 0; j < 4; ++j) kv[j] = *(const float4*)&K[(c0+j)*76 + kk*4];
    #pragma unroll
    for (int i = 0; i < 4; ++i)
      #pragma unroll
      for (int j = 0; j < 4; ++j)
        sc[i][j] += qv[i].x*kv[j].x + qv[i].y*kv[j].y + qv[i].z*kv[j].z + qv[i].w*kv[j].w;
  }
  const float scale = 0.11785113019775793f;   // 72^-0.5
  #pragma unroll
  for (int i = 0; i < 4; ++i){
    float a0 = sc[i][0]*scale, a1 = sc[i][1]*scale, a2 = sc[i][2]*scale, a3 = sc[i][3]*scale;
    float m = fmaxf(fmaxf(a0,a1), fmaxf(a2,a3));
    m = fmaxf(m, __shfl_xor(m, 1, 16));
    m = fmaxf(m, __shfl_xor(m, 2, 16));
    m = fmaxf(m, __shfl_xor(m, 4, 16));
    m = fmaxf(m, __shfl_xor(m, 8, 16));
    float e0 = __expf(a0-m), e1 = __expf(a1-m), e2 = __expf(a2-m), e3 = __expf(a3-m);
    float sm = e0+e1+e2+e3;
    sm += __shfl_xor(sm, 1, 16);
    sm += __shfl_xor(sm, 2, 16);
    sm += __shfl_xor(sm, 4, 16);
    sm += __shfl_xor(sm, 8, 16);
    const float inv = 1.0f/sm;
    *(float4*)&P[(r0+i)*68 + c0] = make_float4(e0*inv, e1*inv, e2*inv, e3*inv);
  }
  __syncthreads();
  for (int d4 = cg; d4 < 18; d4 += 16){
    float4 o[4] = {};
    #pragma unroll 4
    for (int k4 = 0; k4 < 16; ++k4){
      float4 pr[4];
      #pragma unroll
      for (int i = 0; i < 4; ++i) pr[i] = *(const float4*)&P[(r0+i)*68 + k4*4];
      const float4 v0 = *(const float4*)&V[(k4*4+0)*76 + d4*4];
      const float4 v1 = *(const float4*)&V[(k4*4+1)*76 + d4*4];
      const float4 v2 = *(const float4*)&V[(k4*4+2)*76 + d4*4];
      const float4 v3 = *(const float4*)&V[(k4*4+3)*76 + d4*4];
      #pragma unroll
      for (int i = 0; i < 4; ++i){
        o[i].x += pr[i].x*v0.x + pr[i].y*v1.x + pr[i].z*v2.x + pr[i].w*v3.x;
        o[i].y += pr[i].x*v0.y + pr[i].y*v1.y + pr[i].z*v2.y + pr[i].w*v3.y;
        o[i].z += pr[i].x*v0.z + pr[i].y*v1.z + pr[i].z*v2.z + pr[i].w*v3.z;
        o[i].w += pr[i].x*v0.w + pr[i].y*v1.w + pr[i].z*v2.w + pr[i].w*v3.w;
      }
    }
    #pragma unroll
    for (int i = 0; i < 4; ++i){
      const int token = win*64 + r0 + i;
      const size_t ob = (size_t)token*HID + h*HDIM + d4*4;
      outb[ob+0] = f2bf(o[i].x); outb[ob+1] = f2bf(o[i].y);
      outb[ob+2] = f2bf(o[i].z); outb[ob+3] = f2bf(o[i].w);
    }
  }
}

// ---------------- bf16 GEMM: C[M][N] = A[M][K] @ Bt[N][K]^T ----------------
// 128x128 tile, BK=64, 1D grid (size NB*MB, multiple of 8), XCD-grouped tiles.
// LDS layout: 16 chunks per matrix; chunk c = (rowchunk rc = c>>1, k-half h = c&1),
// holds rows rc*16..+15 x 32 K-cols, with XOR swizzle: physical 8-elem slot k holds
// logical chunk k ^ ((row>>1)&3)  (makes every 8 consecutive lanes of ds_read_b128
// hit 8 disjoint bank-quads -> conflict-free).
// EPI: 0 = bf16(bias), 1 = bf16(gelu(bias)), 2 = f32(bias + residual)
template<int EPI>
__global__ __launch_bounds__(256,3) void gemm_bt(
    const uint16_t* __restrict__ A, const uint16_t* __restrict__ Bt,
    const float* __restrict__ bias, int Nb,
    const float* res, void* outp, int N, int K, int NB)
{
  __shared__ uint16_t sA[128*64];
  __shared__ uint16_t sB[128*64];
  const int tid = threadIdx.x, wid = tid >> 6, lane = tid & 63;
  // XCD-grouped tile id: HW dispatches blockIdx round-robin over 8 XCDs;
  // give each XCD a contiguous run of m-strip-major tiles so A-strip sharers
  // (NB consecutive tiles) land in one XCD's L2.
  const int per  = gridDim.x >> 3;
  const int tile = (blockIdx.x & 7)*per + (blockIdx.x >> 3);
  const int mb   = tile / NB;
  const int mBase = mb*128, nBase = (tile - mb*NB)*128;
  const int wm = wid >> 1, wn = wid & 1;
  // staging lane mapping (lane l -> row sr, physical slot sk; fetch logical chunk gk)
  const int sr = lane >> 2;
  const int sk = lane & 3;
  const int gk = sk ^ ((sr >> 1) & 3);
  // fragment read mapping (row rr, logical k-quad rq lives at physical slot rp)
  const int rr = lane & 15;
  const int rq = lane >> 4;
  const int rp = rq ^ ((rr >> 1) & 3);
  f32x4 acc[4][4] = {};

  for (int k0 = 0; k0 < K; k0 += 64){
    __syncthreads();
    #pragma unroll
    for (int j = 0; j < 4; ++j){
      const int c  = wid*4 + j;
      const int rc = c >> 1, h = c & 1;
      const size_t gcol = (size_t)(k0 + h*32 + gk*8);
      async_load16(A  + (size_t)(mBase + rc*16 + sr)*K + gcol, &sA[c*512]);
      async_load16(Bt + (size_t)(nBase + rc*16 + sr)*K + gcol, &sB[c*512]);
    }
    __syncthreads();
    #pragma unroll
    for (int h = 0; h < 2; ++h){
      bf16x8 af[4], bfr[4];
      #pragma unroll
      for (int i = 0; i < 4; ++i)
        af[i] = *(const bf16x8*)&sA[((wm*4 + i)*2 + h)*512 + rr*32 + rp*8];
      #pragma unroll
      for (int j = 0; j < 4; ++j)
        bfr[j] = *(const bf16x8*)&sB[((wn*4 + j)*2 + h)*512 + rr*32 + rp*8];
      #pragma unroll
      for (int i = 0; i < 4; ++i)
        #pragma unroll
        for (int j = 0; j < 4; ++j)
          acc[i][j] = __builtin_amdgcn_mfma_f32_16x16x32_bf16(af[i], bfr[j], acc[i][j], 0, 0, 0);
    }
  }

  const int rqd = (lane>>4)*4, cl = lane & 15;
  #pragma unroll
  for (int i = 0; i < 4; ++i){
    #pragma unroll
    for (int j = 0; j < 4; ++j){
      const int col = nBase + wn*64 + j*16 + cl;
      const float bv = (col < Nb) ? bias[col] : 0.0f;
      #pragma unroll
      for (int r = 0; r < 4; ++r){
        const int row = mBase + wm*64 + i*16 + rqd + r;
        const float v = acc[i][j][r] + bv;
        const size_t o = (size_t)row*N + col;
        if (EPI == 0)      ((uint16_t*)outp)[o] = f2bf(v);
        else if (EPI == 1) ((uint16_t*)outp)[o] = f2bf(gelu_fast(v));
        else               ((float*)outp)[o] = v + res[o];
      }
    }
  }
}

// ---------------- host launcher ----------------
extern "C" void kernel_launch(void* const* d_in, const int* in_sizes, int n_in,
                              void* d_out, int out_size, void* d_ws, size_t ws_size,
                              hipStream_t stream)
{
  const float* x      = (const float*)d_in[0];
  const float* cosb   = (const float*)d_in[1];
  const float* sinb   = (const float*)d_in[2];
  const float* qkv_w  = (const float*)d_in[4];
  const float* qkv_b  = (const float*)d_in[5];
  const float* proj_w = (const float*)d_in[6];
  const float* proj_b = (const float*)d_in[7];
  const float* ln1_w  = (const float*)d_in[8];
  const float* ln1_b  = (const float*)d_in[9];
  const float* ln2_w  = (const float*)d_in[10];
  const float* ln2_b  = (const float*)d_in[11];
  const float* fc1_w  = (const float*)d_in[12];
  const float* fc1_b  = (const float*)d_in[13];
  const float* fc2_w  = (const float*)d_in[14];
  const float* fc2_b  = (const float*)d_in[15];

  char* ws = (char*)d_ws;
  uint16_t* Wqkv  = (uint16_t*)(ws + 0);          // [3456][1152] bf16
  uint16_t* Wproj = (uint16_t*)(ws + 7962624);    // [1152][1152] bf16
  uint16_t* Wfc1  = (uint16_t*)(ws + 10616832);   // [4352][1152] bf16
  uint16_t* Wfc2  = (uint16_t*)(ws + 20643840);   // [1152][4352] bf16
  uint16_t* Hbuf  = (uint16_t*)(ws + 30670848);   // [16384][1152] bf16 (LN out / attn out)
  uint16_t* QKV   = (uint16_t*)(ws + 68419584);   // [16384][3456] bf16
  uint16_t* MB    = QKV;                          // [16384][4352] bf16 overlays QKV
  float* X1 = (float*)d_out;                      // fp32 [16384][1152], residual stream

  // weight transpose+cast (Bt layout [N][K], zero-padded)
  transpose_cast<<<dim3(108,36), 256, 0, stream>>>(qkv_w, Wqkv, 1152, 3456, 1152);
  transpose_cast<<<dim3(36,36),  256, 0, stream>>>(proj_w, Wproj, 1152, 1152, 1152);
  transpose_cast<<<dim3(136,36), 256, 0, stream>>>(fc1_w, Wfc1, 1152, 4304, 1152);
  transpose_cast<<<dim3(36,136), 256, 0, stream>>>(fc2_w, Wfc2, 4304, 1152, 4352);

  // LN1 -> Hbuf (bf16)
  ln_kernel<<<4096, 256, 0, stream>>>(x, ln1_w, ln1_b, Hbuf);
  // QKV = Hbuf @ Wqkv^T + b -> bf16 (unrotated; RoPE applied inside attn)
  gemm_bt<0><<<27*128, 256, 0, stream>>>(Hbuf, Wqkv, qkv_b, QKVN, nullptr, QKV, QKVN, HID, 27);
  // windowed attention with fused RoPE -> Hbuf (bf16)
  attn_kernel<<<4096, 256, 0, stream>>>(QKV, cosb, sinb, Hbuf);
  // X1 = x + Hbuf @ Wproj^T + b  (fp32, into d_out)
  gemm_bt<2><<<9*128, 256, 0, stream>>>(Hbuf, Wproj, proj_b, HID, x, X1, HID, HID, 9);
  // LN2 -> Hbuf (bf16)
  ln_kernel<<<4096, 256, 0, stream>>>(X1, ln2_w, ln2_b, Hbuf);
  // MB = gelu(Hbuf @ Wfc1^T + b)  (bf16, padded N=4352)
  gemm_bt<1><<<34*128, 256, 0, stream>>>(Hbuf, Wfc1, fc1_b, INTER, nullptr, MB, INTERP, HID, 34);
  // out = X1 + MB @ Wfc2^T + b   (fp32, in-place on d_out)
  gemm_bt<2><<<9*128, 256, 0, stream>>>(MB, Wfc2, fc2_b, HID, X1, X1, HID, INTERP, 9);
}

// Round 4
// 1151.594 us; speedup vs baseline: 1.1668x; 1.0073x over previous
//
#include <hip/hip_runtime.h>
#include <stdint.h>

// VisionBlock: LN1 -> QKV GEMM -> [RoPE fused into attn] -> windowed attn (W=64) -> proj+res -> LN2 -> GELU MLP + res
// bf16 MFMA 16x16x32, fp32 accumulate. 128x128 tile, BK=64, global_load_lds width=16,
// XOR bank-conflict swizzle, XCD-grouped tile assignment.
// v4: __launch_bounds__(256,4) -> 4 blocks/CU (LDS 4x32KB=128<=160KB, regs 64+64acc=128=4 waves/SIMD);
//     single merged weight-transpose dispatch (was 4 launches).

#define SEQ   16384
#define HID   1152
#define NH    16
#define HDIM  72
#define INTER 4304
#define INTERP 4352
#define QKVN  3456

using bf16x8 = __attribute__((ext_vector_type(8))) __bf16;
using f32x4  = __attribute__((ext_vector_type(4))) float;

__device__ __forceinline__ float bf2f(uint16_t u){ return __uint_as_float(((uint32_t)u)<<16); }
__device__ __forceinline__ uint16_t f2bf(float f){
  uint32_t u = __float_as_uint(f);
  u += 0x7fffu + ((u>>16)&1u);
  return (uint16_t)(u>>16);
}
// 0.5x(1+tanh(0.79788456(x+0.044715x^3))) == x*sigmoid(1.59576912(x+0.044715x^3))
__device__ __forceinline__ float gelu_fast(float x){
  const float z = 2.3022085f * x * (1.0f + 0.044715f*x*x);
  return x / (1.0f + exp2f(-z));
}
__device__ __forceinline__ void async_load16(const void* g, void* l){
  __builtin_amdgcn_global_load_lds((__attribute__((address_space(1))) void*)(void*)g,
                                   (__attribute__((address_space(3))) void*)l, 16, 0, 0);
}

// ---------------- merged transpose + cast fp32[R][C] -> bf16[Cp][Rp], zero-padded ----------------
// One dispatch covers all 4 weight matrices; job selected by flat block id ranges.
//   job0 qkv : R=1152 C=3456 Rp=1152  grid 108x36 = 3888
//   job1 proj: R=1152 C=1152 Rp=1152  grid  36x36 = 1296
//   job2 fc1 : R=1152 C=4304 Rp=1152  grid 136x36 = 4896
//   job3 fc2 : R=4304 C=1152 Rp=4352  grid  36x136= 4896   (total 14976)
__global__ void transpose_cast_all(const float* __restrict__ s0, uint16_t* __restrict__ d0,
                                   const float* __restrict__ s1, uint16_t* __restrict__ d1,
                                   const float* __restrict__ s2, uint16_t* __restrict__ d2,
                                   const float* __restrict__ s3, uint16_t* __restrict__ d3)
{
  __shared__ float tile[32][33];
  int b = blockIdx.x;
  const float* src; uint16_t* dst; int R, C, Rp, bx, by;
  if (b < 3888){        src = s0; dst = d0; R = 1152; C = 3456; Rp = 1152; bx = b % 108; by = b / 108; }
  else if (b < 5184){   b -= 3888; src = s1; dst = d1; R = 1152; C = 1152; Rp = 1152; bx = b % 36; by = b / 36; }
  else if (b < 10080){  b -= 5184; src = s2; dst = d2; R = 1152; C = 4304; Rp = 1152; bx = b % 136; by = b / 136; }
  else {                b -= 10080; src = s3; dst = d3; R = 4304; C = 1152; Rp = 4352; bx = b % 36; by = b / 36; }
  const int tx = threadIdx.x & 31, ty = threadIdx.x >> 5;
  const int c = bx*32 + tx;
  #pragma unroll
  for (int s = 0; s < 4; ++s){
    const int r = by*32 + ty + s*8;
    tile[ty + s*8][tx] = (r < R && c < C) ? src[(size_t)r*C + c] : 0.0f;
  }
  __syncthreads();
  #pragma unroll
  for (int s = 0; s < 4; ++s){
    const int oc = bx*32 + ty + s*8;     // output row  (N dim)
    const int orr = by*32 + tx;          // output col  (K dim)
    dst[(size_t)oc*Rp + orr] = f2bf(tile[tx][ty + s*8]);
  }
}

// ---------------- LayerNorm: fp32 in -> bf16 out, one wave per row (float2 vectorized) ----------------
__global__ void ln_kernel(const float* __restrict__ x, const float* __restrict__ w,
                          const float* __restrict__ b, uint16_t* __restrict__ out)
{
  const int wid = threadIdx.x >> 6, lane = threadIdx.x & 63;
  const int row = blockIdx.x*4 + wid;
  const float2* xr = (const float2*)(x + (size_t)row*HID);
  float2 v[9];
  float s = 0.f;
  #pragma unroll
  for (int t = 0; t < 9; ++t){ v[t] = xr[lane + t*64]; s += v[t].x + v[t].y; }
  #pragma unroll
  for (int m = 32; m; m >>= 1) s += __shfl_xor(s, m, 64);
  const float mean = s * (1.0f/HID);
  float q = 0.f;
  #pragma unroll
  for (int t = 0; t < 9; ++t){
    float dx = v[t].x-mean, dy = v[t].y-mean;
    q += dx*dx + dy*dy;
  }
  #pragma unroll
  for (int m = 32; m; m >>= 1) q += __shfl_xor(q, m, 64);
  const float rstd = rsqrtf(q*(1.0f/HID) + 1e-6f);
  const float2* w2 = (const float2*)w;
  const float2* b2 = (const float2*)b;
  uint32_t* orow = (uint32_t*)(out + (size_t)row*HID);
  #pragma unroll
  for (int t = 0; t < 9; ++t){
    const int j = lane + t*64;
    const float2 wv = w2[j], bv = b2[j];
    const float o0 = (v[t].x-mean)*rstd*wv.x + bv.x;
    const float o1 = (v[t].y-mean)*rstd*wv.y + bv.y;
    orow[j] = (uint32_t)f2bf(o0) | ((uint32_t)f2bf(o1)<<16);
  }
}

// ---------------- windowed attention with fused RoPE: one block per (window, head) ----------------
// RoPE: for d<36, q'[d] = q[d]*cos[d] - q[d+36]*sin[d]; q'[d+36] = q[d+36]*cos[d] + q[d]*sin[d]
// (cos[d+36]==cos[d] since emb = concat(ang, ang)). Applied while staging into LDS (f32).
__global__ __launch_bounds__(256,2) void attn_kernel(const uint16_t* __restrict__ qkv,
                                                     const float* __restrict__ cosb,
                                                     const float* __restrict__ sinb,
                                                     uint16_t* __restrict__ outb)
{
  __shared__ float Q[64*76];
  __shared__ float K[64*76];
  __shared__ float V[64*76];
  __shared__ float P[64*68];
  const int tid = threadIdx.x;
  const int win = blockIdx.x >> 4, h = blockIdx.x & 15;
  const size_t base = (size_t)win*64*QKVN + h*HDIM;
  {
    const int r = tid >> 2, q4 = tid & 3;
    const size_t rb = base + (size_t)r*QKVN;
    const float* crow = cosb + (size_t)(win*64 + r)*HDIM;
    const float* srow = sinb + (size_t)(win*64 + r)*HDIM;
    const int isK = q4 >> 1;
    const size_t mb = rb + (size_t)(isK ? HID : 0);
    float* dst = isK ? &K[r*76] : &Q[r*76];
    const int pb = (q4 & 1)*9;
    #pragma unroll
    for (int p0 = 0; p0 < 9; ++p0){
      const int d0 = (pb + p0)*2;
      const uint32_t ulo = *(const uint32_t*)(qkv + mb + d0);
      const uint32_t uhi = *(const uint32_t*)(qkv + mb + d0 + 36);
      const float2 c2 = *(const float2*)(crow + d0);
      const float2 s2 = *(const float2*)(srow + d0);
      const float l0 = bf2f((uint16_t)ulo), l1 = bf2f((uint16_t)(ulo>>16));
      const float h0 = bf2f((uint16_t)uhi), h1 = bf2f((uint16_t)(uhi>>16));
      dst[d0]    = l0*c2.x - h0*s2.x;
      dst[d0+1]  = l1*c2.y - h1*s2.y;
      dst[d0+36] = h0*c2.x + l0*s2.x;
      dst[d0+37] = h1*c2.y + l1*s2.y;
    }
    #pragma unroll
    for (int p0 = 0; p0 < 9; ++p0){
      const int p = q4*9 + p0;
      const uint32_t uv = *(const uint32_t*)(qkv + rb + 2*HID + 2*p);
      V[r*76+2*p] = bf2f((uint16_t)uv); V[r*76+2*p+1] = bf2f((uint16_t)(uv>>16));
    }
  }
  __syncthreads();
  const int rg = tid >> 4, cg = tid & 15;
  const int r0 = rg*4, c0 = cg*4;
  float sc[4][4] = {};
  #pragma unroll 3
  for (int kk = 0; kk < 18; ++kk){
    float4 qv[4], kv[4];
    #pragma unroll
    for (int i = 0; i < 4; ++i) qv[i] = *(const float4*)&Q[(r0+i)*76 + kk*4];
    #pragma unroll
    for (int j = 0; j < 4; ++j) kv[j] = *(const float4*)&K[(c0+j)*76 + kk*4];
    #pragma unroll
    for (int i = 0; i < 4; ++i)
      #pragma unroll
      for (int j = 0; j < 4; ++j)
        sc[i][j] += qv[i].x*kv[j].x + qv[i].y*kv[j].y + qv[i].z*kv[j].z + qv[i].w*kv[j].w;
  }
  const float scale = 0.11785113019775793f;   // 72^-0.5
  #pragma unroll
  for (int i = 0; i < 4; ++i){
    float a0 = sc[i][0]*scale, a1 = sc[i][1]*scale, a2 = sc[i][2]*scale, a3 = sc[i][3]*scale;
    float m = fmaxf(fmaxf(a0,a1), fmaxf(a2,a3));
    m = fmaxf(m, __shfl_xor(m, 1, 16));
    m = fmaxf(m, __shfl_xor(m, 2, 16));
    m = fmaxf(m, __shfl_xor(m, 4, 16));
    m = fmaxf(m, __shfl_xor(m, 8, 16));
    float e0 = __expf(a0-m), e1 = __expf(a1-m), e2 = __expf(a2-m), e3 = __expf(a3-m);
    float sm = e0+e1+e2+e3;
    sm += __shfl_xor(sm, 1, 16);
    sm += __shfl_xor(sm, 2, 16);
    sm += __shfl_xor(sm, 4, 16);
    sm += __shfl_xor(sm, 8, 16);
    const float inv = 1.0f/sm;
    *(float4*)&P[(r0+i)*68 + c0] = make_float4(e0*inv, e1*inv, e2*inv, e3*inv);
  }
  __syncthreads();
  for (int d4 = cg; d4 < 18; d4 += 16){
    float4 o[4] = {};
    #pragma unroll 4
    for (int k4 = 0; k4 < 16; ++k4){
      float4 pr[4];
      #pragma unroll
      for (int i = 0; i < 4; ++i) pr[i] = *(const float4*)&P[(r0+i)*68 + k4*4];
      const float4 v0 = *(const float4*)&V[(k4*4+0)*76 + d4*4];
      const float4 v1 = *(const float4*)&V[(k4*4+1)*76 + d4*4];
      const float4 v2 = *(const float4*)&V[(k4*4+2)*76 + d4*4];
      const float4 v3 = *(const float4*)&V[(k4*4+3)*76 + d4*4];
      #pragma unroll
      for (int i = 0; i < 4; ++i){
        o[i].x += pr[i].x*v0.x + pr[i].y*v1.x + pr[i].z*v2.x + pr[i].w*v3.x;
        o[i].y += pr[i].x*v0.y + pr[i].y*v1.y + pr[i].z*v2.y + pr[i].w*v3.y;
        o[i].z += pr[i].x*v0.z + pr[i].y*v1.z + pr[i].z*v2.z + pr[i].w*v3.z;
        o[i].w += pr[i].x*v0.w + pr[i].y*v1.w + pr[i].z*v2.w + pr[i].w*v3.w;
      }
    }
    #pragma unroll
    for (int i = 0; i < 4; ++i){
      const int token = win*64 + r0 + i;
      const size_t ob = (size_t)token*HID + h*HDIM + d4*4;
      outb[ob+0] = f2bf(o[i].x); outb[ob+1] = f2bf(o[i].y);
      outb[ob+2] = f2bf(o[i].z); outb[ob+3] = f2bf(o[i].w);
    }
  }
}

// ---------------- bf16 GEMM: C[M][N] = A[M][K] @ Bt[N][K]^T ----------------
// 128x128 tile, BK=64, 1D grid (size NB*MB, multiple of 8), XCD-grouped tiles.
// LDS layout: 16 chunks per matrix; chunk c = (rowchunk rc = c>>1, k-half h = c&1),
// holds rows rc*16..+15 x 32 K-cols, with XOR swizzle: physical 8-elem slot k holds
// logical chunk k ^ ((row>>1)&3)  (conflict-free ds_read_b128, measured 0 conflicts).
// 4 blocks/CU: LDS 4x32KB=128KB, regs 64 arch + 64 acc = 128 unified = 4 waves/SIMD.
// EPI: 0 = bf16(bias), 1 = bf16(gelu(bias)), 2 = f32(bias + residual)
template<int EPI>
__global__ __launch_bounds__(256,4) void gemm_bt(
    const uint16_t* __restrict__ A, const uint16_t* __restrict__ Bt,
    const float* __restrict__ bias, int Nb,
    const float* res, void* outp, int N, int K, int NB)
{
  __shared__ uint16_t sA[128*64];
  __shared__ uint16_t sB[128*64];
  const int tid = threadIdx.x, wid = tid >> 6, lane = tid & 63;
  const int per  = gridDim.x >> 3;
  const int tile = (blockIdx.x & 7)*per + (blockIdx.x >> 3);
  const int mb   = tile / NB;
  const int mBase = mb*128, nBase = (tile - mb*NB)*128;
  const int wm = wid >> 1, wn = wid & 1;
  const int sr = lane >> 2;
  const int sk = lane & 3;
  const int gk = sk ^ ((sr >> 1) & 3);
  const int rr = lane & 15;
  const int rq = lane >> 4;
  const int rp = rq ^ ((rr >> 1) & 3);
  f32x4 acc[4][4] = {};

  for (int k0 = 0; k0 < K; k0 += 64){
    __syncthreads();
    #pragma unroll
    for (int j = 0; j < 4; ++j){
      const int c  = wid*4 + j;
      const int rc = c >> 1, h = c & 1;
      const size_t gcol = (size_t)(k0 + h*32 + gk*8);
      async_load16(A  + (size_t)(mBase + rc*16 + sr)*K + gcol, &sA[c*512]);
      async_load16(Bt + (size_t)(nBase + rc*16 + sr)*K + gcol, &sB[c*512]);
    }
    __syncthreads();
    #pragma unroll
    for (int h = 0; h < 2; ++h){
      bf16x8 af[4], bfr[4];
      #pragma unroll
      for (int i = 0; i < 4; ++i)
        af[i] = *(const bf16x8*)&sA[((wm*4 + i)*2 + h)*512 + rr*32 + rp*8];
      #pragma unroll
      for (int j = 0; j < 4; ++j)
        bfr[j] = *(const bf16x8*)&sB[((wn*4 + j)*2 + h)*512 + rr*32 + rp*8];
      #pragma unroll
      for (int i = 0; i < 4; ++i)
        #pragma unroll
        for (int j = 0; j < 4; ++j)
          acc[i][j] = __builtin_amdgcn_mfma_f32_16x16x32_bf16(af[i], bfr[j], acc[i][j], 0, 0, 0);
    }
  }

  const int rqd = (lane>>4)*4, cl = lane & 15;
  #pragma unroll
  for (int i = 0; i < 4; ++i){
    #pragma unroll
    for (int j = 0; j < 4; ++j){
      const int col = nBase + wn*64 + j*16 + cl;
      const float bv = (col < Nb) ? bias[col] : 0.0f;
      #pragma unroll
      for (int r = 0; r < 4; ++r){
        const int row = mBase + wm*64 + i*16 + rqd + r;
        const float v = acc[i][j][r] + bv;
        const size_t o = (size_t)row*N + col;
        if (EPI == 0)      ((uint16_t*)outp)[o] = f2bf(v);
        else if (EPI == 1) ((uint16_t*)outp)[o] = f2bf(gelu_fast(v));
        else               ((float*)outp)[o] = v + res[o];
      }
    }
  }
}

// ---------------- host launcher ----------------
extern "C" void kernel_launch(void* const* d_in, const int* in_sizes, int n_in,
                              void* d_out, int out_size, void* d_ws, size_t ws_size,
                              hipStream_t stream)
{
  const float* x      = (const float*)d_in[0];
  const float* cosb   = (const float*)d_in[1];
  const float* sinb   = (const float*)d_in[2];
  const float* qkv_w  = (const float*)d_in[4];
  const float* qkv_b  = (const float*)d_in[5];
  const float* proj_w = (const float*)d_in[6];
  const float* proj_b = (const float*)d_in[7];
  const float* ln1_w  = (const float*)d_in[8];
  const float* ln1_b  = (const float*)d_in[9];
  const float* ln2_w  = (const float*)d_in[10];
  const float* ln2_b  = (const float*)d_in[11];
  const float* fc1_w  = (const float*)d_in[12];
  const float* fc1_b  = (const float*)d_in[13];
  const float* fc2_w  = (const float*)d_in[14];
  const float* fc2_b  = (const float*)d_in[15];

  char* ws = (char*)d_ws;
  uint16_t* Wqkv  = (uint16_t*)(ws + 0);          // [3456][1152] bf16
  uint16_t* Wproj = (uint16_t*)(ws + 7962624);    // [1152][1152] bf16
  uint16_t* Wfc1  = (uint16_t*)(ws + 10616832);   // [4352][1152] bf16
  uint16_t* Wfc2  = (uint16_t*)(ws + 20643840);   // [1152][4352] bf16
  uint16_t* Hbuf  = (uint16_t*)(ws + 30670848);   // [16384][1152] bf16 (LN out / attn out)
  uint16_t* QKV   = (uint16_t*)(ws + 68419584);   // [16384][3456] bf16
  uint16_t* MB    = QKV;                          // [16384][4352] bf16 overlays QKV
  float* X1 = (float*)d_out;                      // fp32 [16384][1152], residual stream

  // all 4 weight transposes in one dispatch (Bt layout [N][K], zero-padded)
  transpose_cast_all<<<14976, 256, 0, stream>>>(qkv_w, Wqkv, proj_w, Wproj,
                                                fc1_w, Wfc1, fc2_w, Wfc2);

  // LN1 -> Hbuf (bf16)
  ln_kernel<<<4096, 256, 0, stream>>>(x, ln1_w, ln1_b, Hbuf);
  // QKV = Hbuf @ Wqkv^T + b -> bf16 (unrotated; RoPE applied inside attn)
  gemm_bt<0><<<27*128, 256, 0, stream>>>(Hbuf, Wqkv, qkv_b, QKVN, nullptr, QKV, QKVN, HID, 27);
  // windowed attention with fused RoPE -> Hbuf (bf16)
  attn_kernel<<<4096, 256, 0, stream>>>(QKV, cosb, sinb, Hbuf);
  // X1 = x + Hbuf @ Wproj^T + b  (fp32, into d_out)
  gemm_bt<2><<<9*128, 256, 0, stream>>>(Hbuf, Wproj, proj_b, HID, x, X1, HID, HID, 9);
  // LN2 -> Hbuf (bf16)
  ln_kernel<<<4096, 256, 0, stream>>>(X1, ln2_w, ln2_b, Hbuf);
  // MB = gelu(Hbuf @ Wfc1^T + b)  (bf16, padded N=4352)
  gemm_bt<1><<<34*128, 256, 0, stream>>>(Hbuf, Wfc1, fc1_b, INTER, nullptr, MB, INTERP, HID, 34);
  // out = X1 + MB @ Wfc2^T + b   (fp32, in-place on d_out)
  gemm_bt<2><<<9*128, 256, 0, stream>>>(MB, Wfc2, fc2_b, HID, X1, X1, HID, INTERP, 9);
}

// Round 5
// 1072.750 us; speedup vs baseline: 1.2526x; 1.0735x over previous
//
#include <hip/hip_runtime.h>
#include <stdint.h>

// VisionBlock: LN1 -> QKV GEMM -> [RoPE fused into attn] -> windowed attn (W=64) -> proj+res -> LN2 -> GELU MLP + res
// bf16 MFMA 16x16x32, fp32 accumulate. 128xN tile (N=128 or 96 via NWJ), BK=64,
// global_load_lds width=16, XOR bank-conflict swizzle, XCD-grouped tiles, 3 blocks/CU.
// v5: NWJ=3 (96-wide n-tiles) for qkv/proj/fc2 -> integral scheduling rounds
//     (proj/fc2: 1536 blocks = exactly 2 rounds; qkv: 4608 = 6 rounds);
//     fc1 stays NWJ=4 (must zero-fill MB cols up to 4352 for fc2's K-pad).
//     launch_bounds back to (256,3) (R4 showed (256,4) shrinks VGPR->56 and slows 9%).

#define SEQ   16384
#define HID   1152
#define NH    16
#define HDIM  72
#define INTER 4304
#define INTERP 4352
#define QKVN  3456

using bf16x8 = __attribute__((ext_vector_type(8))) __bf16;
using f32x4  = __attribute__((ext_vector_type(4))) float;

__device__ __forceinline__ float bf2f(uint16_t u){ return __uint_as_float(((uint32_t)u)<<16); }
__device__ __forceinline__ uint16_t f2bf(float f){
  uint32_t u = __float_as_uint(f);
  u += 0x7fffu + ((u>>16)&1u);
  return (uint16_t)(u>>16);
}
// 0.5x(1+tanh(0.79788456(x+0.044715x^3))) == x*sigmoid(1.59576912(x+0.044715x^3))
__device__ __forceinline__ float gelu_fast(float x){
  const float z = 2.3022085f * x * (1.0f + 0.044715f*x*x);
  return x / (1.0f + exp2f(-z));
}
__device__ __forceinline__ void async_load16(const void* g, void* l){
  __builtin_amdgcn_global_load_lds((__attribute__((address_space(1))) void*)(void*)g,
                                   (__attribute__((address_space(3))) void*)l, 16, 0, 0);
}

// ---------------- merged transpose + cast fp32[R][C] -> bf16[Cp][Rp], zero-padded ----------------
//   job0 qkv : R=1152 C=3456 Rp=1152  grid 108x36 = 3888
//   job1 proj: R=1152 C=1152 Rp=1152  grid  36x36 = 1296
//   job2 fc1 : R=1152 C=4304 Rp=1152  grid 136x36 = 4896
//   job3 fc2 : R=4304 C=1152 Rp=4352  grid  36x136= 4896   (total 14976)
__global__ void transpose_cast_all(const float* __restrict__ s0, uint16_t* __restrict__ d0,
                                   const float* __restrict__ s1, uint16_t* __restrict__ d1,
                                   const float* __restrict__ s2, uint16_t* __restrict__ d2,
                                   const float* __restrict__ s3, uint16_t* __restrict__ d3)
{
  __shared__ float tile[32][33];
  int b = blockIdx.x;
  const float* src; uint16_t* dst; int R, C, Rp, bx, by;
  if (b < 3888){        src = s0; dst = d0; R = 1152; C = 3456; Rp = 1152; bx = b % 108; by = b / 108; }
  else if (b < 5184){   b -= 3888; src = s1; dst = d1; R = 1152; C = 1152; Rp = 1152; bx = b % 36; by = b / 36; }
  else if (b < 10080){  b -= 5184; src = s2; dst = d2; R = 1152; C = 4304; Rp = 1152; bx = b % 136; by = b / 136; }
  else {                b -= 10080; src = s3; dst = d3; R = 4304; C = 1152; Rp = 4352; bx = b % 36; by = b / 36; }
  const int tx = threadIdx.x & 31, ty = threadIdx.x >> 5;
  const int c = bx*32 + tx;
  #pragma unroll
  for (int s = 0; s < 4; ++s){
    const int r = by*32 + ty + s*8;
    tile[ty + s*8][tx] = (r < R && c < C) ? src[(size_t)r*C + c] : 0.0f;
  }
  __syncthreads();
  #pragma unroll
  for (int s = 0; s < 4; ++s){
    const int oc = bx*32 + ty + s*8;     // output row  (N dim)
    const int orr = by*32 + tx;          // output col  (K dim)
    dst[(size_t)oc*Rp + orr] = f2bf(tile[tx][ty + s*8]);
  }
}

// ---------------- LayerNorm: fp32 in -> bf16 out, one wave per row (float2 vectorized) ----------------
__global__ void ln_kernel(const float* __restrict__ x, const float* __restrict__ w,
                          const float* __restrict__ b, uint16_t* __restrict__ out)
{
  const int wid = threadIdx.x >> 6, lane = threadIdx.x & 63;
  const int row = blockIdx.x*4 + wid;
  const float2* xr = (const float2*)(x + (size_t)row*HID);
  float2 v[9];
  float s = 0.f;
  #pragma unroll
  for (int t = 0; t < 9; ++t){ v[t] = xr[lane + t*64]; s += v[t].x + v[t].y; }
  #pragma unroll
  for (int m = 32; m; m >>= 1) s += __shfl_xor(s, m, 64);
  const float mean = s * (1.0f/HID);
  float q = 0.f;
  #pragma unroll
  for (int t = 0; t < 9; ++t){
    float dx = v[t].x-mean, dy = v[t].y-mean;
    q += dx*dx + dy*dy;
  }
  #pragma unroll
  for (int m = 32; m; m >>= 1) q += __shfl_xor(q, m, 64);
  const float rstd = rsqrtf(q*(1.0f/HID) + 1e-6f);
  const float2* w2 = (const float2*)w;
  const float2* b2 = (const float2*)b;
  uint32_t* orow = (uint32_t*)(out + (size_t)row*HID);
  #pragma unroll
  for (int t = 0; t < 9; ++t){
    const int j = lane + t*64;
    const float2 wv = w2[j], bv = b2[j];
    const float o0 = (v[t].x-mean)*rstd*wv.x + bv.x;
    const float o1 = (v[t].y-mean)*rstd*wv.y + bv.y;
    orow[j] = (uint32_t)f2bf(o0) | ((uint32_t)f2bf(o1)<<16);
  }
}

// ---------------- windowed attention with fused RoPE: one block per (window, head) ----------------
// RoPE: for d<36, q'[d] = q[d]*cos[d] - q[d+36]*sin[d]; q'[d+36] = q[d+36]*cos[d] + q[d]*sin[d]
// (cos[d+36]==cos[d] since emb = concat(ang, ang)). Applied while staging into LDS (f32).
__global__ __launch_bounds__(256,2) void attn_kernel(const uint16_t* __restrict__ qkv,
                                                     const float* __restrict__ cosb,
                                                     const float* __restrict__ sinb,
                                                     uint16_t* __restrict__ outb)
{
  __shared__ float Q[64*76];
  __shared__ float K[64*76];
  __shared__ float V[64*76];
  __shared__ float P[64*68];
  const int tid = threadIdx.x;
  const int win = blockIdx.x >> 4, h = blockIdx.x & 15;
  const size_t base = (size_t)win*64*QKVN + h*HDIM;
  {
    const int r = tid >> 2, q4 = tid & 3;
    const size_t rb = base + (size_t)r*QKVN;
    const float* crow = cosb + (size_t)(win*64 + r)*HDIM;
    const float* srow = sinb + (size_t)(win*64 + r)*HDIM;
    const int isK = q4 >> 1;
    const size_t mb = rb + (size_t)(isK ? HID : 0);
    float* dst = isK ? &K[r*76] : &Q[r*76];
    const int pb = (q4 & 1)*9;
    #pragma unroll
    for (int p0 = 0; p0 < 9; ++p0){
      const int d0 = (pb + p0)*2;
      const uint32_t ulo = *(const uint32_t*)(qkv + mb + d0);
      const uint32_t uhi = *(const uint32_t*)(qkv + mb + d0 + 36);
      const float2 c2 = *(const float2*)(crow + d0);
      const float2 s2 = *(const float2*)(srow + d0);
      const float l0 = bf2f((uint16_t)ulo), l1 = bf2f((uint16_t)(ulo>>16));
      const float h0 = bf2f((uint16_t)uhi), h1 = bf2f((uint16_t)(uhi>>16));
      dst[d0]    = l0*c2.x - h0*s2.x;
      dst[d0+1]  = l1*c2.y - h1*s2.y;
      dst[d0+36] = h0*c2.x + l0*s2.x;
      dst[d0+37] = h1*c2.y + l1*s2.y;
    }
    #pragma unroll
    for (int p0 = 0; p0 < 9; ++p0){
      const int p = q4*9 + p0;
      const uint32_t uv = *(const uint32_t*)(qkv + rb + 2*HID + 2*p);
      V[r*76+2*p] = bf2f((uint16_t)uv); V[r*76+2*p+1] = bf2f((uint16_t)(uv>>16));
    }
  }
  __syncthreads();
  const int rg = tid >> 4, cg = tid & 15;
  const int r0 = rg*4, c0 = cg*4;
  float sc[4][4] = {};
  #pragma unroll 3
  for (int kk = 0; kk < 18; ++kk){
    float4 qv[4], kv[4];
    #pragma unroll
    for (int i = 0; i < 4; ++i) qv[i] = *(const float4*)&Q[(r0+i)*76 + kk*4];
    #pragma unroll
    for (int j = 0; j < 4; ++j) kv[j] = *(const float4*)&K[(c0+j)*76 + kk*4];
    #pragma unroll
    for (int i = 0; i < 4; ++i)
      #pragma unroll
      for (int j = 0; j < 4; ++j)
        sc[i][j] += qv[i].x*kv[j].x + qv[i].y*kv[j].y + qv[i].z*kv[j].z + qv[i].w*kv[j].w;
  }
  const float scale = 0.11785113019775793f;   // 72^-0.5
  #pragma unroll
  for (int i = 0; i < 4; ++i){
    float a0 = sc[i][0]*scale, a1 = sc[i][1]*scale, a2 = sc[i][2]*scale, a3 = sc[i][3]*scale;
    float m = fmaxf(fmaxf(a0,a1), fmaxf(a2,a3));
    m = fmaxf(m, __shfl_xor(m, 1, 16));
    m = fmaxf(m, __shfl_xor(m, 2, 16));
    m = fmaxf(m, __shfl_xor(m, 4, 16));
    m = fmaxf(m, __shfl_xor(m, 8, 16));
    float e0 = __expf(a0-m), e1 = __expf(a1-m), e2 = __expf(a2-m), e3 = __expf(a3-m);
    float sm = e0+e1+e2+e3;
    sm += __shfl_xor(sm, 1, 16);
    sm += __shfl_xor(sm, 2, 16);
    sm += __shfl_xor(sm, 4, 16);
    sm += __shfl_xor(sm, 8, 16);
    const float inv = 1.0f/sm;
    *(float4*)&P[(r0+i)*68 + c0] = make_float4(e0*inv, e1*inv, e2*inv, e3*inv);
  }
  __syncthreads();
  for (int d4 = cg; d4 < 18; d4 += 16){
    float4 o[4] = {};
    #pragma unroll 4
    for (int k4 = 0; k4 < 16; ++k4){
      float4 pr[4];
      #pragma unroll
      for (int i = 0; i < 4; ++i) pr[i] = *(const float4*)&P[(r0+i)*68 + k4*4];
      const float4 v0 = *(const float4*)&V[(k4*4+0)*76 + d4*4];
      const float4 v1 = *(const float4*)&V[(k4*4+1)*76 + d4*4];
      const float4 v2 = *(const float4*)&V[(k4*4+2)*76 + d4*4];
      const float4 v3 = *(const float4*)&V[(k4*4+3)*76 + d4*4];
      #pragma unroll
      for (int i = 0; i < 4; ++i){
        o[i].x += pr[i].x*v0.x + pr[i].y*v1.x + pr[i].z*v2.x + pr[i].w*v3.x;
        o[i].y += pr[i].x*v0.y + pr[i].y*v1.y + pr[i].z*v2.y + pr[i].w*v3.y;
        o[i].z += pr[i].x*v0.z + pr[i].y*v1.z + pr[i].z*v2.z + pr[i].w*v3.z;
        o[i].w += pr[i].x*v0.w + pr[i].y*v1.w + pr[i].z*v2.w + pr[i].w*v3.w;
      }
    }
    #pragma unroll
    for (int i = 0; i < 4; ++i){
      const int token = win*64 + r0 + i;
      const size_t ob = (size_t)token*HID + h*HDIM + d4*4;
      outb[ob+0] = f2bf(o[i].x); outb[ob+1] = f2bf(o[i].y);
      outb[ob+2] = f2bf(o[i].z); outb[ob+3] = f2bf(o[i].w);
    }
  }
}

// ---------------- bf16 GEMM: C[M][N] = A[M][K] @ Bt[N][K]^T ----------------
// 128 x (32*NWJ) tile, BK=64, 1D grid (NB*MB, multiple of 8), XCD-grouped tiles.
// LDS: A 16 chunks, B 4*NWJ chunks; chunk c = (rowchunk rc = c>>1, k-half h = c&1),
// 16 rows x 32 K-cols, XOR swizzle: physical 8-elem slot k holds logical chunk
// k ^ ((row>>1)&3)  (conflict-free ds_read_b128, measured 0 conflicts).
// NWJ=4: 128-wide n-tile (acc[4][4]); NWJ=3: 96-wide n-tile (acc[4][3]) for
// integral scheduling rounds at 3 blocks/CU (proj/fc2 grid 1536 = 2 exact rounds).
// EPI: 0 = bf16(bias), 1 = bf16(gelu(bias)), 2 = f32(bias + residual)
template<int EPI, int NWJ>
__global__ __launch_bounds__(256,3) void gemm_bt(
    const uint16_t* __restrict__ A, const uint16_t* __restrict__ Bt,
    const float* __restrict__ bias, int Nb,
    const float* res, void* outp, int N, int K, int NB)
{
  __shared__ uint16_t sA[128*64];
  __shared__ uint16_t sB[32*NWJ*64];
  const int tid = threadIdx.x, wid = tid >> 6, lane = tid & 63;
  const int per  = gridDim.x >> 3;
  const int tile = (blockIdx.x & 7)*per + (blockIdx.x >> 3);
  const int mb   = tile / NB;
  const int mBase = mb*128, nBase = (tile - mb*NB)*(32*NWJ);
  const int wm = wid >> 1, wn = wid & 1;
  const int sr = lane >> 2;
  const int sk = lane & 3;
  const int gk = sk ^ ((sr >> 1) & 3);
  const int rr = lane & 15;
  const int rq = lane >> 4;
  const int rp = rq ^ ((rr >> 1) & 3);
  f32x4 acc[4][NWJ] = {};

  for (int k0 = 0; k0 < K; k0 += 64){
    __syncthreads();
    #pragma unroll
    for (int j = 0; j < 4; ++j){
      const int c  = wid*4 + j;
      const int rc = c >> 1, h = c & 1;
      const size_t gcol = (size_t)(k0 + h*32 + gk*8);
      async_load16(A + (size_t)(mBase + rc*16 + sr)*K + gcol, &sA[c*512]);
    }
    #pragma unroll
    for (int j = 0; j < NWJ; ++j){
      const int c  = wid*NWJ + j;
      const int rc = c >> 1, h = c & 1;
      const size_t gcol = (size_t)(k0 + h*32 + gk*8);
      async_load16(Bt + (size_t)(nBase + rc*16 + sr)*K + gcol, &sB[c*512]);
    }
    __syncthreads();
    #pragma unroll
    for (int h = 0; h < 2; ++h){
      bf16x8 af[4], bfr[NWJ];
      #pragma unroll
      for (int i = 0; i < 4; ++i)
        af[i] = *(const bf16x8*)&sA[((wm*4 + i)*2 + h)*512 + rr*32 + rp*8];
      #pragma unroll
      for (int j = 0; j < NWJ; ++j)
        bfr[j] = *(const bf16x8*)&sB[((wn*NWJ + j)*2 + h)*512 + rr*32 + rp*8];
      #pragma unroll
      for (int i = 0; i < 4; ++i)
        #pragma unroll
        for (int j = 0; j < NWJ; ++j)
          acc[i][j] = __builtin_amdgcn_mfma_f32_16x16x32_bf16(af[i], bfr[j], acc[i][j], 0, 0, 0);
    }
  }

  const int rqd = (lane>>4)*4, cl = lane & 15;
  #pragma unroll
  for (int i = 0; i < 4; ++i){
    #pragma unroll
    for (int j = 0; j < NWJ; ++j){
      const int col = nBase + wn*(NWJ*16) + j*16 + cl;
      const float bv = (col < Nb) ? bias[col] : 0.0f;
      #pragma unroll
      for (int r = 0; r < 4; ++r){
        const int row = mBase + wm*64 + i*16 + rqd + r;
        const float v = acc[i][j][r] + bv;
        const size_t o = (size_t)row*N + col;
        if (EPI == 0)      ((uint16_t*)outp)[o] = f2bf(v);
        else if (EPI == 1) ((uint16_t*)outp)[o] = f2bf(gelu_fast(v));
        else               ((float*)outp)[o] = v + res[o];
      }
    }
  }
}

// ---------------- host launcher ----------------
extern "C" void kernel_launch(void* const* d_in, const int* in_sizes, int n_in,
                              void* d_out, int out_size, void* d_ws, size_t ws_size,
                              hipStream_t stream)
{
  const float* x      = (const float*)d_in[0];
  const float* cosb   = (const float*)d_in[1];
  const float* sinb   = (const float*)d_in[2];
  const float* qkv_w  = (const float*)d_in[4];
  const float* qkv_b  = (const float*)d_in[5];
  const float* proj_w = (const float*)d_in[6];
  const float* proj_b = (const float*)d_in[7];
  const float* ln1_w  = (const float*)d_in[8];
  const float* ln1_b  = (const float*)d_in[9];
  const float* ln2_w  = (const float*)d_in[10];
  const float* ln2_b  = (const float*)d_in[11];
  const float* fc1_w  = (const float*)d_in[12];
  const float* fc1_b  = (const float*)d_in[13];
  const float* fc2_w  = (const float*)d_in[14];
  const float* fc2_b  = (const float*)d_in[15];

  char* ws = (char*)d_ws;
  uint16_t* Wqkv  = (uint16_t*)(ws + 0);          // [3456][1152] bf16
  uint16_t* Wproj = (uint16_t*)(ws + 7962624);    // [1152][1152] bf16
  uint16_t* Wfc1  = (uint16_t*)(ws + 10616832);   // [4352][1152] bf16
  uint16_t* Wfc2  = (uint16_t*)(ws + 20643840);   // [1152][4352] bf16
  uint16_t* Hbuf  = (uint16_t*)(ws + 30670848);   // [16384][1152] bf16 (LN out / attn out)
  uint16_t* QKV   = (uint16_t*)(ws + 68419584);   // [16384][3456] bf16
  uint16_t* MB    = QKV;                          // [16384][4352] bf16 overlays QKV
  float* X1 = (float*)d_out;                      // fp32 [16384][1152], residual stream

  // all 4 weight transposes in one dispatch (Bt layout [N][K], zero-padded)
  transpose_cast_all<<<14976, 256, 0, stream>>>(qkv_w, Wqkv, proj_w, Wproj,
                                                fc1_w, Wfc1, fc2_w, Wfc2);

  // LN1 -> Hbuf (bf16)
  ln_kernel<<<4096, 256, 0, stream>>>(x, ln1_w, ln1_b, Hbuf);
  // QKV = Hbuf @ Wqkv^T + b -> bf16 (unrotated; RoPE inside attn). 36x96 n-tiles, 6 exact rounds.
  gemm_bt<0,3><<<36*128, 256, 0, stream>>>(Hbuf, Wqkv, qkv_b, QKVN, nullptr, QKV, QKVN, HID, 36);
  // windowed attention with fused RoPE -> Hbuf (bf16)
  attn_kernel<<<4096, 256, 0, stream>>>(QKV, cosb, sinb, Hbuf);
  // X1 = x + Hbuf @ Wproj^T + b  (fp32, into d_out). 12x96 n-tiles, 2 exact rounds.
  gemm_bt<2,3><<<12*128, 256, 0, stream>>>(Hbuf, Wproj, proj_b, HID, x, X1, HID, HID, 12);
  // LN2 -> Hbuf (bf16)
  ln_kernel<<<4096, 256, 0, stream>>>(X1, ln2_w, ln2_b, Hbuf);
  // MB = gelu(Hbuf @ Wfc1^T + b)  (bf16, padded N=4352: keeps MB K-pad zero for fc2)
  gemm_bt<1,4><<<34*128, 256, 0, stream>>>(Hbuf, Wfc1, fc1_b, INTER, nullptr, MB, INTERP, HID, 34);
  // out = X1 + MB @ Wfc2^T + b   (fp32, in-place on d_out). 12x96 n-tiles, 2 exact rounds.
  gemm_bt<2,3><<<12*128, 256, 0, stream>>>(MB, Wfc2, fc2_b, HID, X1, X1, HID, INTERP, 12);
}

// Round 6
// 1000.232 us; speedup vs baseline: 1.3434x; 1.0725x over previous
//
#include <hip/hip_runtime.h>
#include <stdint.h>

// VisionBlock: LN1 -> QKV GEMM -> [RoPE fused into attn] -> MFMA windowed attn (W=64) -> proj+res -> LN2 -> GELU MLP + res
// bf16 MFMA 16x16x32, fp32 accumulate everywhere.
// GEMM: 128x(32*NWJ) tile, BK=64, global_load_lds w=16, XOR swizzle, XCD-grouped, 3 blk/CU (R5 config).
// v6: attention rewritten on MFMA: Q,K bf16 LDS (K-dim padded 72->96), V transposed Vt[80][64],
//     P bf16 in LDS (wave-private rows), per-wave 16-row strips; softmax on C/D register layout.

#define SEQ   16384
#define HID   1152
#define NH    16
#define HDIM  72
#define INTER 4304
#define INTERP 4352
#define QKVN  3456

using bf16x8 = __attribute__((ext_vector_type(8))) __bf16;
using f32x4  = __attribute__((ext_vector_type(4))) float;

__device__ __forceinline__ float bf2f(uint16_t u){ return __uint_as_float(((uint32_t)u)<<16); }
__device__ __forceinline__ uint16_t f2bf(float f){
  uint32_t u = __float_as_uint(f);
  u += 0x7fffu + ((u>>16)&1u);
  return (uint16_t)(u>>16);
}
__device__ __forceinline__ uint32_t pk2(uint16_t a, uint16_t b){ return (uint32_t)a | ((uint32_t)b<<16); }
// 0.5x(1+tanh(0.79788456(x+0.044715x^3))) == x*sigmoid(1.59576912(x+0.044715x^3))
__device__ __forceinline__ float gelu_fast(float x){
  const float z = 2.3022085f * x * (1.0f + 0.044715f*x*x);
  return x / (1.0f + exp2f(-z));
}
__device__ __forceinline__ void async_load16(const void* g, void* l){
  __builtin_amdgcn_global_load_lds((__attribute__((address_space(1))) void*)(void*)g,
                                   (__attribute__((address_space(3))) void*)l, 16, 0, 0);
}

// ---------------- merged transpose + cast fp32[R][C] -> bf16[Cp][Rp], zero-padded ----------------
__global__ void transpose_cast_all(const float* __restrict__ s0, uint16_t* __restrict__ d0,
                                   const float* __restrict__ s1, uint16_t* __restrict__ d1,
                                   const float* __restrict__ s2, uint16_t* __restrict__ d2,
                                   const float* __restrict__ s3, uint16_t* __restrict__ d3)
{
  __shared__ float tile[32][33];
  int b = blockIdx.x;
  const float* src; uint16_t* dst; int R, C, Rp, bx, by;
  if (b < 3888){        src = s0; dst = d0; R = 1152; C = 3456; Rp = 1152; bx = b % 108; by = b / 108; }
  else if (b < 5184){   b -= 3888; src = s1; dst = d1; R = 1152; C = 1152; Rp = 1152; bx = b % 36; by = b / 36; }
  else if (b < 10080){  b -= 5184; src = s2; dst = d2; R = 1152; C = 4304; Rp = 1152; bx = b % 136; by = b / 136; }
  else {                b -= 10080; src = s3; dst = d3; R = 4304; C = 1152; Rp = 4352; bx = b % 36; by = b / 36; }
  const int tx = threadIdx.x & 31, ty = threadIdx.x >> 5;
  const int c = bx*32 + tx;
  #pragma unroll
  for (int s = 0; s < 4; ++s){
    const int r = by*32 + ty + s*8;
    tile[ty + s*8][tx] = (r < R && c < C) ? src[(size_t)r*C + c] : 0.0f;
  }
  __syncthreads();
  #pragma unroll
  for (int s = 0; s < 4; ++s){
    const int oc = bx*32 + ty + s*8;     // output row  (N dim)
    const int orr = by*32 + tx;          // output col  (K dim)
    dst[(size_t)oc*Rp + orr] = f2bf(tile[tx][ty + s*8]);
  }
}

// ---------------- LayerNorm: fp32 in -> bf16 out, one wave per row (float2 vectorized) ----------------
__global__ void ln_kernel(const float* __restrict__ x, const float* __restrict__ w,
                          const float* __restrict__ b, uint16_t* __restrict__ out)
{
  const int wid = threadIdx.x >> 6, lane = threadIdx.x & 63;
  const int row = blockIdx.x*4 + wid;
  const float2* xr = (const float2*)(x + (size_t)row*HID);
  float2 v[9];
  float s = 0.f;
  #pragma unroll
  for (int t = 0; t < 9; ++t){ v[t] = xr[lane + t*64]; s += v[t].x + v[t].y; }
  #pragma unroll
  for (int m = 32; m; m >>= 1) s += __shfl_xor(s, m, 64);
  const float mean = s * (1.0f/HID);
  float q = 0.f;
  #pragma unroll
  for (int t = 0; t < 9; ++t){
    float dx = v[t].x-mean, dy = v[t].y-mean;
    q += dx*dx + dy*dy;
  }
  #pragma unroll
  for (int m = 32; m; m >>= 1) q += __shfl_xor(q, m, 64);
  const float rstd = rsqrtf(q*(1.0f/HID) + 1e-6f);
  const float2* w2 = (const float2*)w;
  const float2* b2 = (const float2*)b;
  uint32_t* orow = (uint32_t*)(out + (size_t)row*HID);
  #pragma unroll
  for (int t = 0; t < 9; ++t){
    const int j = lane + t*64;
    const float2 wv = w2[j], bv = b2[j];
    const float o0 = (v[t].x-mean)*rstd*wv.x + bv.x;
    const float o1 = (v[t].y-mean)*rstd*wv.y + bv.y;
    orow[j] = (uint32_t)f2bf(o0) | ((uint32_t)f2bf(o1)<<16);
  }
}

// ---------------- MFMA windowed attention with fused RoPE: one block per (window, head) ----------------
// Layouts (bf16 LDS):
//   Qb[64][104]: rows = tokens, cols = dims, dims 72..95 zeroed (K-pad for 3x 16x16x32), stride 104 (208 B,
//                8 consecutive rows cover all 32 banks for b128 frag reads; 16 rows -> free 2-way).
//   Kb[64][104]: same.
//   Vt[80][72-stride]: rows = dims (72 real + 8 zero pad), cols = tokens; stride 72 elems (144 B).
//   Pb[64][72-stride]: probs, rows = q-tokens, cols = k-tokens (64), stride 72.
// Per wave (4 waves): 16-row output strip. QK^T: A=Q strip, Bt=K (3 k-steps x 4 n-tiles = 12 MFMA).
// Softmax on C/D layout (col=lane&15, row=(lane>>4)*4+reg), shfl_xor width-16 row reduce -> Pb bf16.
// PV: A=Pb strip (k=64 tokens, 2 k-steps), Bt=Vt (5 n-tiles of dims) = 10 MFMA. P rows are wave-private.
__global__ __launch_bounds__(256,3) void attn_kernel(const uint16_t* __restrict__ qkv,
                                                     const float* __restrict__ cosb,
                                                     const float* __restrict__ sinb,
                                                     uint16_t* __restrict__ outb)
{
  __shared__ uint16_t Qb[64*104];
  __shared__ uint16_t Kb[64*104];
  __shared__ uint16_t Vt[80*72];
  __shared__ uint16_t Pb[64*72];
  const int tid = threadIdx.x;
  const int win = blockIdx.x >> 4, h = blockIdx.x & 15;
  const size_t base = (size_t)win*64*QKVN + h*HDIM;
  // ---- staging: RoPE(Q,K) -> bf16, V transposed ----
  {
    const int r = tid >> 2, q4 = tid & 3;
    const size_t rb = base + (size_t)r*QKVN;
    const float* crow = cosb + (size_t)(win*64 + r)*HDIM;
    const float* srow = sinb + (size_t)(win*64 + r)*HDIM;
    const int isK = q4 >> 1;
    const size_t mb = rb + (size_t)(isK ? HID : 0);
    uint16_t* dst = isK ? &Kb[r*104] : &Qb[r*104];
    const int pb = (q4 & 1)*9;
    #pragma unroll
    for (int p0 = 0; p0 < 9; ++p0){
      const int d0 = (pb + p0)*2;
      const uint32_t ulo = *(const uint32_t*)(qkv + mb + d0);
      const uint32_t uhi = *(const uint32_t*)(qkv + mb + d0 + 36);
      const float2 c2 = *(const float2*)(crow + d0);
      const float2 s2 = *(const float2*)(srow + d0);
      const float l0 = bf2f((uint16_t)ulo), l1 = bf2f((uint16_t)(ulo>>16));
      const float h0 = bf2f((uint16_t)uhi), h1 = bf2f((uint16_t)(uhi>>16));
      *(uint32_t*)&dst[d0]    = pk2(f2bf(l0*c2.x - h0*s2.x), f2bf(l1*c2.y - h1*s2.y));
      *(uint32_t*)&dst[d0+36] = pk2(f2bf(h0*c2.x + l0*s2.x), f2bf(h1*c2.y + l1*s2.y));
    }
    // zero dims 72..95 of this row (12 uint32 split between the 2 threads per matrix)
    const int zb = (q4 & 1)*6;
    #pragma unroll
    for (int z = 0; z < 6; ++z) *(uint32_t*)&dst[72 + (zb + z)*2] = 0;
    // V transposed: dims 2p,2p+1 of token r
    #pragma unroll
    for (int p0 = 0; p0 < 9; ++p0){
      const int p = q4*9 + p0;
      const uint32_t uv = *(const uint32_t*)(qkv + rb + 2*HID + 2*p);
      Vt[(2*p+0)*72 + r] = (uint16_t)uv;
      Vt[(2*p+1)*72 + r] = (uint16_t)(uv>>16);
    }
  }
  // zero Vt pad rows 72..79 (8 dims x 64 tokens = 256 uint32, one per thread)
  {
    const int d = 72 + (tid >> 5), t = (tid & 31)*2;
    *(uint32_t*)&Vt[d*72 + t] = 0;
  }
  __syncthreads();

  const int wv = tid >> 6, lane = tid & 63;
  const int fr = lane & 15, fq = lane >> 4;
  // ---- QK^T: scores strip rows wv*16..+15, cols 0..63 ----
  f32x4 sacc[4] = {};
  #pragma unroll
  for (int ks = 0; ks < 3; ++ks){
    const bf16x8 aq = *(const bf16x8*)&Qb[(wv*16 + fr)*104 + ks*32 + fq*8];
    #pragma unroll
    for (int j = 0; j < 4; ++j){
      const bf16x8 bk = *(const bf16x8*)&Kb[(j*16 + fr)*104 + ks*32 + fq*8];
      sacc[j] = __builtin_amdgcn_mfma_f32_16x16x32_bf16(aq, bk, sacc[j], 0, 0, 0);
    }
  }
  // ---- softmax on C/D layout; write P as bf16 ----
  const float scale = 0.11785113019775793f;   // 72^-0.5
  #pragma unroll
  for (int r = 0; r < 4; ++r){
    float a0 = sacc[0][r]*scale, a1 = sacc[1][r]*scale, a2 = sacc[2][r]*scale, a3 = sacc[3][r]*scale;
    float m = fmaxf(fmaxf(a0,a1), fmaxf(a2,a3));
    m = fmaxf(m, __shfl_xor(m, 1, 16));
    m = fmaxf(m, __shfl_xor(m, 2, 16));
    m = fmaxf(m, __shfl_xor(m, 4, 16));
    m = fmaxf(m, __shfl_xor(m, 8, 16));
    float e0 = __expf(a0-m), e1 = __expf(a1-m), e2 = __expf(a2-m), e3 = __expf(a3-m);
    float sm = e0+e1+e2+e3;
    sm += __shfl_xor(sm, 1, 16);
    sm += __shfl_xor(sm, 2, 16);
    sm += __shfl_xor(sm, 4, 16);
    sm += __shfl_xor(sm, 8, 16);
    const float inv = 1.0f/sm;
    const int prow = wv*16 + fq*4 + r;
    Pb[prow*72 +  0 + fr] = f2bf(e0*inv);
    Pb[prow*72 + 16 + fr] = f2bf(e1*inv);
    Pb[prow*72 + 32 + fr] = f2bf(e2*inv);
    Pb[prow*72 + 48 + fr] = f2bf(e3*inv);
  }
  // P rows wv*16..+15 are written and read by wave wv only -> no barrier needed (lgkmcnt ordering).
  // ---- PV: out strip rows wv*16..+15, dims 0..71 (5 n-tiles, last half-padded) ----
  f32x4 oacc[5] = {};
  #pragma unroll
  for (int k2 = 0; k2 < 2; ++k2){
    const bf16x8 ap = *(const bf16x8*)&Pb[(wv*16 + fr)*72 + k2*32 + fq*8];
    #pragma unroll
    for (int j = 0; j < 5; ++j){
      const bf16x8 bv = *(const bf16x8*)&Vt[(j*16 + fr)*72 + k2*32 + fq*8];
      oacc[j] = __builtin_amdgcn_mfma_f32_16x16x32_bf16(ap, bv, oacc[j], 0, 0, 0);
    }
  }
  // ---- store: C/D layout col=dim, row=token ----
  #pragma unroll
  for (int j = 0; j < 5; ++j){
    const int d = j*16 + fr;
    if (d < HDIM){
      #pragma unroll
      for (int r = 0; r < 4; ++r){
        const int token = win*64 + wv*16 + fq*4 + r;
        outb[(size_t)token*HID + h*HDIM + d] = f2bf(oacc[j][r]);
      }
    }
  }
}

// ---------------- bf16 GEMM: C[M][N] = A[M][K] @ Bt[N][K]^T ----------------
// 128 x (32*NWJ) tile, BK=64, 1D grid (NB*MB, multiple of 8), XCD-grouped tiles.
// XOR swizzle: physical 8-elem slot k holds logical chunk k ^ ((row>>1)&3) (0 conflicts measured).
// NWJ=4: 128-wide n-tile; NWJ=3: 96-wide (integral rounds at 3 blk/CU for qkv/proj/fc2).
// EPI: 0 = bf16(bias), 1 = bf16(gelu(bias)), 2 = f32(bias + residual)
template<int EPI, int NWJ>
__global__ __launch_bounds__(256,3) void gemm_bt(
    const uint16_t* __restrict__ A, const uint16_t* __restrict__ Bt,
    const float* __restrict__ bias, int Nb,
    const float* res, void* outp, int N, int K, int NB)
{
  __shared__ uint16_t sA[128*64];
  __shared__ uint16_t sB[32*NWJ*64];
  const int tid = threadIdx.x, wid = tid >> 6, lane = tid & 63;
  const int per  = gridDim.x >> 3;
  const int tile = (blockIdx.x & 7)*per + (blockIdx.x >> 3);
  const int mb   = tile / NB;
  const int mBase = mb*128, nBase = (tile - mb*NB)*(32*NWJ);
  const int wm = wid >> 1, wn = wid & 1;
  const int sr = lane >> 2;
  const int sk = lane & 3;
  const int gk = sk ^ ((sr >> 1) & 3);
  const int rr = lane & 15;
  const int rq = lane >> 4;
  const int rp = rq ^ ((rr >> 1) & 3);
  f32x4 acc[4][NWJ] = {};

  for (int k0 = 0; k0 < K; k0 += 64){
    __syncthreads();
    #pragma unroll
    for (int j = 0; j < 4; ++j){
      const int c  = wid*4 + j;
      const int rc = c >> 1, h = c & 1;
      const size_t gcol = (size_t)(k0 + h*32 + gk*8);
      async_load16(A + (size_t)(mBase + rc*16 + sr)*K + gcol, &sA[c*512]);
    }
    #pragma unroll
    for (int j = 0; j < NWJ; ++j){
      const int c  = wid*NWJ + j;
      const int rc = c >> 1, h = c & 1;
      const size_t gcol = (size_t)(k0 + h*32 + gk*8);
      async_load16(Bt + (size_t)(nBase + rc*16 + sr)*K + gcol, &sB[c*512]);
    }
    __syncthreads();
    #pragma unroll
    for (int h = 0; h < 2; ++h){
      bf16x8 af[4], bfr[NWJ];
      #pragma unroll
      for (int i = 0; i < 4; ++i)
        af[i] = *(const bf16x8*)&sA[((wm*4 + i)*2 + h)*512 + rr*32 + rp*8];
      #pragma unroll
      for (int j = 0; j < NWJ; ++j)
        bfr[j] = *(const bf16x8*)&sB[((wn*NWJ + j)*2 + h)*512 + rr*32 + rp*8];
      #pragma unroll
      for (int i = 0; i < 4; ++i)
        #pragma unroll
        for (int j = 0; j < NWJ; ++j)
          acc[i][j] = __builtin_amdgcn_mfma_f32_16x16x32_bf16(af[i], bfr[j], acc[i][j], 0, 0, 0);
    }
  }

  const int rqd = (lane>>4)*4, cl = lane & 15;
  #pragma unroll
  for (int i = 0; i < 4; ++i){
    #pragma unroll
    for (int j = 0; j < NWJ; ++j){
      const int col = nBase + wn*(NWJ*16) + j*16 + cl;
      const float bv = (col < Nb) ? bias[col] : 0.0f;
      #pragma unroll
      for (int r = 0; r < 4; ++r){
        const int row = mBase + wm*64 + i*16 + rqd + r;
        const float v = acc[i][j][r] + bv;
        const size_t o = (size_t)row*N + col;
        if (EPI == 0)      ((uint16_t*)outp)[o] = f2bf(v);
        else if (EPI == 1) ((uint16_t*)outp)[o] = f2bf(gelu_fast(v));
        else               ((float*)outp)[o] = v + res[o];
      }
    }
  }
}

// ---------------- host launcher ----------------
extern "C" void kernel_launch(void* const* d_in, const int* in_sizes, int n_in,
                              void* d_out, int out_size, void* d_ws, size_t ws_size,
                              hipStream_t stream)
{
  const float* x      = (const float*)d_in[0];
  const float* cosb   = (const float*)d_in[1];
  const float* sinb   = (const float*)d_in[2];
  const float* qkv_w  = (const float*)d_in[4];
  const float* qkv_b  = (const float*)d_in[5];
  const float* proj_w = (const float*)d_in[6];
  const float* proj_b = (const float*)d_in[7];
  const float* ln1_w  = (const float*)d_in[8];
  const float* ln1_b  = (const float*)d_in[9];
  const float* ln2_w  = (const float*)d_in[10];
  const float* ln2_b  = (const float*)d_in[11];
  const float* fc1_w  = (const float*)d_in[12];
  const float* fc1_b  = (const float*)d_in[13];
  const float* fc2_w  = (const float*)d_in[14];
  const float* fc2_b  = (const float*)d_in[15];

  char* ws = (char*)d_ws;
  uint16_t* Wqkv  = (uint16_t*)(ws + 0);          // [3456][1152] bf16
  uint16_t* Wproj = (uint16_t*)(ws + 7962624);    // [1152][1152] bf16
  uint16_t* Wfc1  = (uint16_t*)(ws + 10616832);   // [4352][1152] bf16
  uint16_t* Wfc2  = (uint16_t*)(ws + 20643840);   // [1152][4352] bf16
  uint16_t* Hbuf  = (uint16_t*)(ws + 30670848);   // [16384][1152] bf16 (LN out / attn out)
  uint16_t* QKV   = (uint16_t*)(ws + 68419584);   // [16384][3456] bf16
  uint16_t* MB    = QKV;                          // [16384][4352] bf16 overlays QKV
  float* X1 = (float*)d_out;                      // fp32 [16384][1152], residual stream

  // all 4 weight transposes in one dispatch (Bt layout [N][K], zero-padded)
  transpose_cast_all<<<14976, 256, 0, stream>>>(qkv_w, Wqkv, proj_w, Wproj,
                                                fc1_w, Wfc1, fc2_w, Wfc2);

  // LN1 -> Hbuf (bf16)
  ln_kernel<<<4096, 256, 0, stream>>>(x, ln1_w, ln1_b, Hbuf);
  // QKV = Hbuf @ Wqkv^T + b -> bf16 (unrotated; RoPE inside attn). 36x96 n-tiles, 6 exact rounds.
  gemm_bt<0,3><<<36*128, 256, 0, stream>>>(Hbuf, Wqkv, qkv_b, QKVN, nullptr, QKV, QKVN, HID, 36);
  // MFMA windowed attention with fused RoPE -> Hbuf (bf16)
  attn_kernel<<<4096, 256, 0, stream>>>(QKV, cosb, sinb, Hbuf);
  // X1 = x + Hbuf @ Wproj^T + b  (fp32, into d_out). 12x96 n-tiles, 2 exact rounds.
  gemm_bt<2,3><<<12*128, 256, 0, stream>>>(Hbuf, Wproj, proj_b, HID, x, X1, HID, HID, 12);
  // LN2 -> Hbuf (bf16)
  ln_kernel<<<4096, 256, 0, stream>>>(X1, ln2_w, ln2_b, Hbuf);
  // MB = gelu(Hbuf @ Wfc1^T + b)  (bf16, padded N=4352: keeps MB K-pad zero for fc2)
  gemm_bt<1,4><<<34*128, 256, 0, stream>>>(Hbuf, Wfc1, fc1_b, INTER, nullptr, MB, INTERP, HID, 34);
  // out = X1 + MB @ Wfc2^T + b   (fp32, in-place on d_out). 12x96 n-tiles, 2 exact rounds.
  gemm_bt<2,3><<<12*128, 256, 0, stream>>>(MB, Wfc2, fc2_b, HID, X1, X1, HID, INTERP, 12);
}

// Round 7
// 998.999 us; speedup vs baseline: 1.3450x; 1.0012x over previous
//
#include <hip/hip_runtime.h>
#include <stdint.h>

// VisionBlock: LN1 -> QKV GEMM -> [RoPE fused into attn] -> MFMA windowed attn (W=64) -> proj+res -> LN2 -> GELU MLP + res
// bf16 MFMA 16x16x32, fp32 accumulate everywhere.
// GEMM: 128x(32*NWJ) tile, BK=64, global_load_lds w=16, XOR swizzle, XCD-grouped, 3 blk/CU (R5 config).
// v7: attn P overlays dead Q LDS (wave-private 16-row strips -> race-free, no barrier);
//     LDS 47.4->38.1 KB => 4 blocks/CU and grid 4096 = exactly 4.0 rounds;
//     s_setprio(1) around attn MFMA clusters (independent-wave regime, m191-positive).

#define SEQ   16384
#define HID   1152
#define NH    16
#define HDIM  72
#define INTER 4304
#define INTERP 4352
#define QKVN  3456

using bf16x8 = __attribute__((ext_vector_type(8))) __bf16;
using f32x4  = __attribute__((ext_vector_type(4))) float;

__device__ __forceinline__ float bf2f(uint16_t u){ return __uint_as_float(((uint32_t)u)<<16); }
__device__ __forceinline__ uint16_t f2bf(float f){
  uint32_t u = __float_as_uint(f);
  u += 0x7fffu + ((u>>16)&1u);
  return (uint16_t)(u>>16);
}
__device__ __forceinline__ uint32_t pk2(uint16_t a, uint16_t b){ return (uint32_t)a | ((uint32_t)b<<16); }
// 0.5x(1+tanh(0.79788456(x+0.044715x^3))) == x*sigmoid(1.59576912(x+0.044715x^3))
__device__ __forceinline__ float gelu_fast(float x){
  const float z = 2.3022085f * x * (1.0f + 0.044715f*x*x);
  return x / (1.0f + exp2f(-z));
}
__device__ __forceinline__ void async_load16(const void* g, void* l){
  __builtin_amdgcn_global_load_lds((__attribute__((address_space(1))) void*)(void*)g,
                                   (__attribute__((address_space(3))) void*)l, 16, 0, 0);
}

// ---------------- merged transpose + cast fp32[R][C] -> bf16[Cp][Rp], zero-padded ----------------
__global__ void transpose_cast_all(const float* __restrict__ s0, uint16_t* __restrict__ d0,
                                   const float* __restrict__ s1, uint16_t* __restrict__ d1,
                                   const float* __restrict__ s2, uint16_t* __restrict__ d2,
                                   const float* __restrict__ s3, uint16_t* __restrict__ d3)
{
  __shared__ float tile[32][33];
  int b = blockIdx.x;
  const float* src; uint16_t* dst; int R, C, Rp, bx, by;
  if (b < 3888){        src = s0; dst = d0; R = 1152; C = 3456; Rp = 1152; bx = b % 108; by = b / 108; }
  else if (b < 5184){   b -= 3888; src = s1; dst = d1; R = 1152; C = 1152; Rp = 1152; bx = b % 36; by = b / 36; }
  else if (b < 10080){  b -= 5184; src = s2; dst = d2; R = 1152; C = 4304; Rp = 1152; bx = b % 136; by = b / 136; }
  else {                b -= 10080; src = s3; dst = d3; R = 4304; C = 1152; Rp = 4352; bx = b % 36; by = b / 36; }
  const int tx = threadIdx.x & 31, ty = threadIdx.x >> 5;
  const int c = bx*32 + tx;
  #pragma unroll
  for (int s = 0; s < 4; ++s){
    const int r = by*32 + ty + s*8;
    tile[ty + s*8][tx] = (r < R && c < C) ? src[(size_t)r*C + c] : 0.0f;
  }
  __syncthreads();
  #pragma unroll
  for (int s = 0; s < 4; ++s){
    const int oc = bx*32 + ty + s*8;     // output row  (N dim)
    const int orr = by*32 + tx;          // output col  (K dim)
    dst[(size_t)oc*Rp + orr] = f2bf(tile[tx][ty + s*8]);
  }
}

// ---------------- LayerNorm: fp32 in -> bf16 out, one wave per row (float2 vectorized) ----------------
__global__ void ln_kernel(const float* __restrict__ x, const float* __restrict__ w,
                          const float* __restrict__ b, uint16_t* __restrict__ out)
{
  const int wid = threadIdx.x >> 6, lane = threadIdx.x & 63;
  const int row = blockIdx.x*4 + wid;
  const float2* xr = (const float2*)(x + (size_t)row*HID);
  float2 v[9];
  float s = 0.f;
  #pragma unroll
  for (int t = 0; t < 9; ++t){ v[t] = xr[lane + t*64]; s += v[t].x + v[t].y; }
  #pragma unroll
  for (int m = 32; m; m >>= 1) s += __shfl_xor(s, m, 64);
  const float mean = s * (1.0f/HID);
  float q = 0.f;
  #pragma unroll
  for (int t = 0; t < 9; ++t){
    float dx = v[t].x-mean, dy = v[t].y-mean;
    q += dx*dx + dy*dy;
  }
  #pragma unroll
  for (int m = 32; m; m >>= 1) q += __shfl_xor(q, m, 64);
  const float rstd = rsqrtf(q*(1.0f/HID) + 1e-6f);
  const float2* w2 = (const float2*)w;
  const float2* b2 = (const float2*)b;
  uint32_t* orow = (uint32_t*)(out + (size_t)row*HID);
  #pragma unroll
  for (int t = 0; t < 9; ++t){
    const int j = lane + t*64;
    const float2 wv = w2[j], bv = b2[j];
    const float o0 = (v[t].x-mean)*rstd*wv.x + bv.x;
    const float o1 = (v[t].y-mean)*rstd*wv.y + bv.y;
    orow[j] = (uint32_t)f2bf(o0) | ((uint32_t)f2bf(o1)<<16);
  }
}

// ---------------- MFMA windowed attention with fused RoPE: one block per (window, head) ----------------
// Layouts (bf16 LDS):
//   Qb[64][104]: rows = tokens, cols = dims, dims 72..95 zeroed (K-pad), stride 104.
//     After QK^T, cols 0..63 of each row are REUSED as P (probs row-major, stride 104):
//     wave wv reads/writes only rows wv*16..+15 of Q and P -> wave-private, no barrier needed;
//     same-base aliasing keeps compiler ds-op ordering conservative.
//   Kb[64][104]: same layout as Qb (all rows read by all waves).
//   Vt[80][72-stride]: rows = dims (72 real + 8 zero pad), cols = tokens.
// Per wave (4 waves): 16-row strip. QK^T: 3 k-steps x 4 n-tiles = 12 MFMA. Softmax on C/D
// layout (col=lane&15, row=(lane>>4)*4+reg), shfl_xor width-16 -> P bf16. PV: 2 k-steps x
// 5 n-tiles = 10 MFMA. setprio(1) around MFMA clusters (waves independent post-staging).
__global__ __launch_bounds__(256,4) void attn_kernel(const uint16_t* __restrict__ qkv,
                                                     const float* __restrict__ cosb,
                                                     const float* __restrict__ sinb,
                                                     uint16_t* __restrict__ outb)
{
  __shared__ uint16_t Qb[64*104];   // Q, then P overlays cols 0..63
  __shared__ uint16_t Kb[64*104];
  __shared__ uint16_t Vt[80*72];
  const int tid = threadIdx.x;
  const int win = blockIdx.x >> 4, h = blockIdx.x & 15;
  const size_t base = (size_t)win*64*QKVN + h*HDIM;
  // ---- staging: RoPE(Q,K) -> bf16, V transposed ----
  {
    const int r = tid >> 2, q4 = tid & 3;
    const size_t rb = base + (size_t)r*QKVN;
    const float* crow = cosb + (size_t)(win*64 + r)*HDIM;
    const float* srow = sinb + (size_t)(win*64 + r)*HDIM;
    const int isK = q4 >> 1;
    const size_t mb = rb + (size_t)(isK ? HID : 0);
    uint16_t* dst = isK ? &Kb[r*104] : &Qb[r*104];
    const int pb = (q4 & 1)*9;
    #pragma unroll
    for (int p0 = 0; p0 < 9; ++p0){
      const int d0 = (pb + p0)*2;
      const uint32_t ulo = *(const uint32_t*)(qkv + mb + d0);
      const uint32_t uhi = *(const uint32_t*)(qkv + mb + d0 + 36);
      const float2 c2 = *(const float2*)(crow + d0);
      const float2 s2 = *(const float2*)(srow + d0);
      const float l0 = bf2f((uint16_t)ulo), l1 = bf2f((uint16_t)(ulo>>16));
      const float h0 = bf2f((uint16_t)uhi), h1 = bf2f((uint16_t)(uhi>>16));
      *(uint32_t*)&dst[d0]    = pk2(f2bf(l0*c2.x - h0*s2.x), f2bf(l1*c2.y - h1*s2.y));
      *(uint32_t*)&dst[d0+36] = pk2(f2bf(h0*c2.x + l0*s2.x), f2bf(h1*c2.y + l1*s2.y));
    }
    // zero dims 72..95 of this row (12 uint32 split between the 2 threads per matrix)
    const int zb = (q4 & 1)*6;
    #pragma unroll
    for (int z = 0; z < 6; ++z) *(uint32_t*)&dst[72 + (zb + z)*2] = 0;
    // V transposed: dims 2p,2p+1 of token r
    #pragma unroll
    for (int p0 = 0; p0 < 9; ++p0){
      const int p = q4*9 + p0;
      const uint32_t uv = *(const uint32_t*)(qkv + rb + 2*HID + 2*p);
      Vt[(2*p+0)*72 + r] = (uint16_t)uv;
      Vt[(2*p+1)*72 + r] = (uint16_t)(uv>>16);
    }
  }
  // zero Vt pad rows 72..79 (8 dims x 64 tokens = 256 uint32, one per thread)
  {
    const int d = 72 + (tid >> 5), t = (tid & 31)*2;
    *(uint32_t*)&Vt[d*72 + t] = 0;
  }
  __syncthreads();

  const int wv = tid >> 6, lane = tid & 63;
  const int fr = lane & 15, fq = lane >> 4;
  // ---- QK^T: scores strip rows wv*16..+15, cols 0..63 ----
  f32x4 sacc[4] = {};
  __builtin_amdgcn_s_setprio(1);
  #pragma unroll
  for (int ks = 0; ks < 3; ++ks){
    const bf16x8 aq = *(const bf16x8*)&Qb[(wv*16 + fr)*104 + ks*32 + fq*8];
    #pragma unroll
    for (int j = 0; j < 4; ++j){
      const bf16x8 bk = *(const bf16x8*)&Kb[(j*16 + fr)*104 + ks*32 + fq*8];
      sacc[j] = __builtin_amdgcn_mfma_f32_16x16x32_bf16(aq, bk, sacc[j], 0, 0, 0);
    }
  }
  __builtin_amdgcn_s_setprio(0);
  // ---- softmax on C/D layout; write P (bf16) into Qb cols 0..63 (own strip only) ----
  const float scale = 0.11785113019775793f;   // 72^-0.5
  #pragma unroll
  for (int r = 0; r < 4; ++r){
    float a0 = sacc[0][r]*scale, a1 = sacc[1][r]*scale, a2 = sacc[2][r]*scale, a3 = sacc[3][r]*scale;
    float m = fmaxf(fmaxf(a0,a1), fmaxf(a2,a3));
    m = fmaxf(m, __shfl_xor(m, 1, 16));
    m = fmaxf(m, __shfl_xor(m, 2, 16));
    m = fmaxf(m, __shfl_xor(m, 4, 16));
    m = fmaxf(m, __shfl_xor(m, 8, 16));
    float e0 = __expf(a0-m), e1 = __expf(a1-m), e2 = __expf(a2-m), e3 = __expf(a3-m);
    float sm = e0+e1+e2+e3;
    sm += __shfl_xor(sm, 1, 16);
    sm += __shfl_xor(sm, 2, 16);
    sm += __shfl_xor(sm, 4, 16);
    sm += __shfl_xor(sm, 8, 16);
    const float inv = 1.0f/sm;
    const int prow = wv*16 + fq*4 + r;
    Qb[prow*104 +  0 + fr] = f2bf(e0*inv);
    Qb[prow*104 + 16 + fr] = f2bf(e1*inv);
    Qb[prow*104 + 32 + fr] = f2bf(e2*inv);
    Qb[prow*104 + 48 + fr] = f2bf(e3*inv);
  }
  // P rows wv*16..+15 are written and read by wave wv only -> no barrier needed.
  // ---- PV: out strip rows wv*16..+15, dims 0..71 (5 n-tiles, last half-padded) ----
  f32x4 oacc[5] = {};
  __builtin_amdgcn_s_setprio(1);
  #pragma unroll
  for (int k2 = 0; k2 < 2; ++k2){
    const bf16x8 ap = *(const bf16x8*)&Qb[(wv*16 + fr)*104 + k2*32 + fq*8];
    #pragma unroll
    for (int j = 0; j < 5; ++j){
      const bf16x8 bv = *(const bf16x8*)&Vt[(j*16 + fr)*72 + k2*32 + fq*8];
      oacc[j] = __builtin_amdgcn_mfma_f32_16x16x32_bf16(ap, bv, oacc[j], 0, 0, 0);
    }
  }
  __builtin_amdgcn_s_setprio(0);
  // ---- store: C/D layout col=dim, row=token ----
  #pragma unroll
  for (int j = 0; j < 5; ++j){
    const int d = j*16 + fr;
    if (d < HDIM){
      #pragma unroll
      for (int r = 0; r < 4; ++r){
        const int token = win*64 + wv*16 + fq*4 + r;
        outb[(size_t)token*HID + h*HDIM + d] = f2bf(oacc[j][r]);
      }
    }
  }
}

// ---------------- bf16 GEMM: C[M][N] = A[M][K] @ Bt[N][K]^T ----------------
// 128 x (32*NWJ) tile, BK=64, 1D grid (NB*MB, multiple of 8), XCD-grouped tiles.
// XOR swizzle: physical 8-elem slot k holds logical chunk k ^ ((row>>1)&3) (0 conflicts measured).
// NWJ=4: 128-wide n-tile; NWJ=3: 96-wide (integral rounds at 3 blk/CU for qkv/proj/fc2).
// EPI: 0 = bf16(bias), 1 = bf16(gelu(bias)), 2 = f32(bias + residual)
template<int EPI, int NWJ>
__global__ __launch_bounds__(256,3) void gemm_bt(
    const uint16_t* __restrict__ A, const uint16_t* __restrict__ Bt,
    const float* __restrict__ bias, int Nb,
    const float* res, void* outp, int N, int K, int NB)
{
  __shared__ uint16_t sA[128*64];
  __shared__ uint16_t sB[32*NWJ*64];
  const int tid = threadIdx.x, wid = tid >> 6, lane = tid & 63;
  const int per  = gridDim.x >> 3;
  const int tile = (blockIdx.x & 7)*per + (blockIdx.x >> 3);
  const int mb   = tile / NB;
  const int mBase = mb*128, nBase = (tile - mb*NB)*(32*NWJ);
  const int wm = wid >> 1, wn = wid & 1;
  const int sr = lane >> 2;
  const int sk = lane & 3;
  const int gk = sk ^ ((sr >> 1) & 3);
  const int rr = lane & 15;
  const int rq = lane >> 4;
  const int rp = rq ^ ((rr >> 1) & 3);
  f32x4 acc[4][NWJ] = {};

  for (int k0 = 0; k0 < K; k0 += 64){
    __syncthreads();
    #pragma unroll
    for (int j = 0; j < 4; ++j){
      const int c  = wid*4 + j;
      const int rc = c >> 1, h = c & 1;
      const size_t gcol = (size_t)(k0 + h*32 + gk*8);
      async_load16(A + (size_t)(mBase + rc*16 + sr)*K + gcol, &sA[c*512]);
    }
    #pragma unroll
    for (int j = 0; j < NWJ; ++j){
      const int c  = wid*NWJ + j;
      const int rc = c >> 1, h = c & 1;
      const size_t gcol = (size_t)(k0 + h*32 + gk*8);
      async_load16(Bt + (size_t)(nBase + rc*16 + sr)*K + gcol, &sB[c*512]);
    }
    __syncthreads();
    #pragma unroll
    for (int h = 0; h < 2; ++h){
      bf16x8 af[4], bfr[NWJ];
      #pragma unroll
      for (int i = 0; i < 4; ++i)
        af[i] = *(const bf16x8*)&sA[((wm*4 + i)*2 + h)*512 + rr*32 + rp*8];
      #pragma unroll
      for (int j = 0; j < NWJ; ++j)
        bfr[j] = *(const bf16x8*)&sB[((wn*NWJ + j)*2 + h)*512 + rr*32 + rp*8];
      #pragma unroll
      for (int i = 0; i < 4; ++i)
        #pragma unroll
        for (int j = 0; j < NWJ; ++j)
          acc[i][j] = __builtin_amdgcn_mfma_f32_16x16x32_bf16(af[i], bfr[j], acc[i][j], 0, 0, 0);
    }
  }

  const int rqd = (lane>>4)*4, cl = lane & 15;
  #pragma unroll
  for (int i = 0; i < 4; ++i){
    #pragma unroll
    for (int j = 0; j < NWJ; ++j){
      const int col = nBase + wn*(NWJ*16) + j*16 + cl;
      const float bv = (col < Nb) ? bias[col] : 0.0f;
      #pragma unroll
      for (int r = 0; r < 4; ++r){
        const int row = mBase + wm*64 + i*16 + rqd + r;
        const float v = acc[i][j][r] + bv;
        const size_t o = (size_t)row*N + col;
        if (EPI == 0)      ((uint16_t*)outp)[o] = f2bf(v);
        else if (EPI == 1) ((uint16_t*)outp)[o] = f2bf(gelu_fast(v));
        else               ((float*)outp)[o] = v + res[o];
      }
    }
  }
}

// ---------------- host launcher ----------------
extern "C" void kernel_launch(void* const* d_in, const int* in_sizes, int n_in,
                              void* d_out, int out_size, void* d_ws, size_t ws_size,
                              hipStream_t stream)
{
  const float* x      = (const float*)d_in[0];
  const float* cosb   = (const float*)d_in[1];
  const float* sinb   = (const float*)d_in[2];
  const float* qkv_w  = (const float*)d_in[4];
  const float* qkv_b  = (const float*)d_in[5];
  const float* proj_w = (const float*)d_in[6];
  const float* proj_b = (const float*)d_in[7];
  const float* ln1_w  = (const float*)d_in[8];
  const float* ln1_b  = (const float*)d_in[9];
  const float* ln2_w  = (const float*)d_in[10];
  const float* ln2_b  = (const float*)d_in[11];
  const float* fc1_w  = (const float*)d_in[12];
  const float* fc1_b  = (const float*)d_in[13];
  const float* fc2_w  = (const float*)d_in[14];
  const float* fc2_b  = (const float*)d_in[15];

  char* ws = (char*)d_ws;
  uint16_t* Wqkv  = (uint16_t*)(ws + 0);          // [3456][1152] bf16
  uint16_t* Wproj = (uint16_t*)(ws + 7962624);    // [1152][1152] bf16
  uint16_t* Wfc1  = (uint16_t*)(ws + 10616832);   // [4352][1152] bf16
  uint16_t* Wfc2  = (uint16_t*)(ws + 20643840);   // [1152][4352] bf16
  uint16_t* Hbuf  = (uint16_t*)(ws + 30670848);   // [16384][1152] bf16 (LN out / attn out)
  uint16_t* QKV   = (uint16_t*)(ws + 68419584);   // [16384][3456] bf16
  uint16_t* MB    = QKV;                          // [16384][4352] bf16 overlays QKV
  float* X1 = (float*)d_out;                      // fp32 [16384][1152], residual stream

  // all 4 weight transposes in one dispatch (Bt layout [N][K], zero-padded)
  transpose_cast_all<<<14976, 256, 0, stream>>>(qkv_w, Wqkv, proj_w, Wproj,
                                                fc1_w, Wfc1, fc2_w, Wfc2);

  // LN1 -> Hbuf (bf16)
  ln_kernel<<<4096, 256, 0, stream>>>(x, ln1_w, ln1_b, Hbuf);
  // QKV = Hbuf @ Wqkv^T + b -> bf16 (unrotated; RoPE inside attn). 36x96 n-tiles, 6 exact rounds.
  gemm_bt<0,3><<<36*128, 256, 0, stream>>>(Hbuf, Wqkv, qkv_b, QKVN, nullptr, QKV, QKVN, HID, 36);
  // MFMA windowed attention with fused RoPE -> Hbuf (bf16). 4 blk/CU, 4.0 exact rounds.
  attn_kernel<<<4096, 256, 0, stream>>>(QKV, cosb, sinb, Hbuf);
  // X1 = x + Hbuf @ Wproj^T + b  (fp32, into d_out). 12x96 n-tiles, 2 exact rounds.
  gemm_bt<2,3><<<12*128, 256, 0, stream>>>(Hbuf, Wproj, proj_b, HID, x, X1, HID, HID, 12);
  // LN2 -> Hbuf (bf16)
  ln_kernel<<<4096, 256, 0, stream>>>(X1, ln2_w, ln2_b, Hbuf);
  // MB = gelu(Hbuf @ Wfc1^T + b)  (bf16, padded N=4352: keeps MB K-pad zero for fc2)
  gemm_bt<1,4><<<34*128, 256, 0, stream>>>(Hbuf, Wfc1, fc1_b, INTER, nullptr, MB, INTERP, HID, 34);
  // out = X1 + MB @ Wfc2^T + b   (fp32, in-place on d_out). 12x96 n-tiles, 2 exact rounds.
  gemm_bt<2,3><<<12*128, 256, 0, stream>>>(MB, Wfc2, fc2_b, HID, X1, X1, HID, INTERP, 12);
}